// Round 14
// baseline (627.928 us; speedup 1.0000x reference)
//
#include <hip/hip_runtime.h>
#include <hip/hip_bf16.h>
#include <cstdint>

typedef __hip_bfloat16 bf16;
typedef __attribute__((ext_vector_type(8))) short short8;
typedef __attribute__((ext_vector_type(4))) float f32x4;

// ---------------------------------------------------------------------------
// async global->LDS, 16B/lane (wave-uniform LDS base + lane*16 implicit)
// ---------------------------------------------------------------------------
__device__ __forceinline__ void gload16(const bf16* g, bf16* l) {
    __builtin_amdgcn_global_load_lds(
        (__attribute__((address_space(1))) void*)g,
        (__attribute__((address_space(3))) void*)l, 16, 0, 0);
}
#define VMC(n) asm volatile("s_waitcnt vmcnt(" #n ")" ::: "memory")
#define LGKM0 asm volatile("s_waitcnt lgkmcnt(0)" ::: "memory")
__device__ __forceinline__ void bar() {
    asm volatile("" ::: "memory");
    __builtin_amdgcn_s_barrier();
    asm volatile("" ::: "memory");
}

// ---------------------------------------------------------------------------
// stage one half-tile [128 rows x 64 cols bf16] into a linear LDS region.
// Source pre-swizzled: LDS(r, slot) = G(r, slot ^ (r&7)) [16B slots].
// ---------------------------------------------------------------------------
__device__ __forceinline__ void stage_half(const bf16* __restrict__ G, int ld,
                                           int row0, int k0, bf16* lregion,
                                           int w, int lrow, int lslot)
{
    const bf16* s0 = G + (long long)(row0 + w * 8 + lrow) * ld + (k0 + lslot * 8);
    gload16(s0, lregion + (w * 64) * 8);
    gload16(s0 + (long long)64 * ld, lregion + (512 + w * 64) * 8);
}

#define LOAD_AI(dst, i_, mh, P) do { \
    _Pragma("unroll") for (int ks_ = 0; ks_ < 2; ++ks_) \
      dst[i_][ks_] = *(const short8*)((P) + ((mh) * 64 + (i_) * 16 + l15) * 64 \
                                         + (((ks_ * 4 + lq) ^ l7) * 8)); } while (0)
#define LOAD_B(nh, dst) do { _Pragma("unroll") for (int j_ = 0; j_ < 2; ++j_) { \
    _Pragma("unroll") for (int ks_ = 0; ks_ < 2; ++ks_) \
      dst[j_][ks_] = *(const short8*)(pb + (bhr + (nh) * 32 + j_ * 16 + l15) * 64 \
                                         + (((ks_ * 4 + lq) ^ l7) * 8)); } } while (0)
#define DO_Q(mh, nh, AF, BF) do { \
    __builtin_amdgcn_s_setprio(1); \
    _Pragma("unroll") for (int i_ = 0; i_ < 4; ++i_) \
      _Pragma("unroll") for (int j_ = 0; j_ < 2; ++j_) \
        _Pragma("unroll") for (int ks_ = 0; ks_ < 2; ++ks_) \
          acc[mh][nh][i_][j_] = __builtin_amdgcn_mfma_f32_16x16x32_bf16( \
              AF[i_][ks_], BF[j_][ks_], acc[mh][nh][i_][j_], 0, 0, 0); \
    __builtin_amdgcn_s_setprio(0); \
} while (0)

// ---------------------------------------------------------------------------
// 256x256 bf16 GEMM core, C = A*B^T (+bias)(+leakyrelu). 64 KiB LDS
// (single-buffered A,B -> 2 blocks/CU). Ledger (full drains only):
//   reads(16 ds_read) -> Q(0,0),Q(0,1)            [compiler lgkm overlap]
//   LGKM0; bar()                                  [all waves' reads done]
//   stage t+1 (8 gloads, same regions)            [safe overwrite]
//   Q(1,1),Q(1,0)                                 [covers gload latency]
//   VMC(0); bar()                                 [staged data visible]
// regions: A0=+0, A1=+8192, B0=+16384, B1=+24576 (bf16 units).
// BIASMODE: 0 none; 1 bias[gc]; 3 bias[bz*512+gc] (energy c[t] term).
// ROUTE: 0 single output; 2 dual (gc<1024 -> v2T direct; else q' ld 1088).
// ---------------------------------------------------------------------------
template<int OUT_BF16, int ACT, int BIASMODE, int ROUTE>
__device__ __forceinline__ void gemm_core(
    bf16* ldsb,
    const bf16* __restrict__ Abase, const bf16* __restrict__ Bbase,
    void* __restrict__ Cbase, const float* __restrict__ bias,
    int K, int lda, int ldb, int ldc, int nwrite,
    long long sA, long long sB, long long sC, long long segStride,
    int bx, int by, int bz)
{
    const int tid = threadIdx.x;
    const int wid = tid >> 6, lane = tid & 63;
    const int wm = wid >> 2, wn = wid & 3;          // 2 x 4 waves
    const int l15 = lane & 15, l7 = lane & 7, lq = lane >> 4;
    const int lrow = lane >> 3, lslot = l7 ^ lrow;  // staging per-lane geom
    const int bhr = (wn & 1) * 64;                  // B row base within half

    const bf16* A = Abase + (long long)bz * sA;
    const bf16* B = Bbase + (long long)bz * sB;
    const int brow = by * 256, bcol = bx * 256;

    f32x4 acc[2][2][4][2] = {};
    short8 aFe[4][2], aFo[4][2], bF0[2][2], bF1[2][2];

    const int nt = K >> 6;

    // ---- prologue: stage tile 0, full drain ----
    stage_half(B, ldb, bcol,       0, ldsb + 2 * 8192, wid, lrow, lslot);
    stage_half(B, ldb, bcol + 128, 0, ldsb + 3 * 8192, wid, lrow, lslot);
    stage_half(A, lda, brow,       0, ldsb,            wid, lrow, lslot);
    stage_half(A, lda, brow + 128, 0, ldsb + 8192,     wid, lrow, lslot);
    VMC(0);
    bar();

    const bf16* pa = ldsb + wm * 8192;
    const bf16* pb = ldsb + 16384 + (wn >> 1) * 8192;

    for (int t = 0; t < nt; ++t) {
        const int t1 = (t + 1 == nt) ? 0 : t + 1;
        const int k1 = t1 << 6;

        // ---- all fragment reads for tile t ----
        LOAD_B(0, bF0);
        LOAD_AI(aFe, 0, 0, pa); LOAD_AI(aFe, 1, 0, pa);
        LOAD_AI(aFe, 2, 0, pa); LOAD_AI(aFe, 3, 0, pa);
        LOAD_B(1, bF1);
        LOAD_AI(aFo, 0, 1, pa); LOAD_AI(aFo, 1, 1, pa);
        LOAD_AI(aFo, 2, 1, pa); LOAD_AI(aFo, 3, 1, pa);

        // ---- first half of MFMAs overlaps the read drain ----
        DO_Q(0, 0, aFe, bF0);
        DO_Q(0, 1, aFe, bF1);

        LGKM0;   // own reads complete; barrier => all waves' reads complete
        bar();

        // ---- stage tile t+1 into the same regions (async) ----
        stage_half(B, ldb, bcol,       k1, ldsb + 2 * 8192, wid, lrow, lslot);
        stage_half(B, ldb, bcol + 128, k1, ldsb + 3 * 8192, wid, lrow, lslot);
        stage_half(A, lda, brow,       k1, ldsb,            wid, lrow, lslot);
        stage_half(A, lda, brow + 128, k1, ldsb + 8192,     wid, lrow, lslot);

        // ---- second half of MFMAs covers the gload latency ----
        DO_Q(1, 1, aFo, bF1);
        DO_Q(1, 0, aFo, bF0);

        VMC(0);   // staged tile t+1 fully landed
        bar();
    }

    // ---- epilogue: C/D layout col = lane&15, row = (lane>>4)*4 + rr ----
    const long long cofs0 = (long long)bz * sC;
    #pragma unroll
    for (int mh = 0; mh < 2; ++mh)
      #pragma unroll
      for (int nh = 0; nh < 2; ++nh)
        #pragma unroll
        for (int i = 0; i < 4; ++i)
          #pragma unroll
          for (int j = 0; j < 2; ++j) {
              const int gc = bcol + wn * 64 + nh * 32 + j * 16 + l15;
              const bool wr = gc < nwrite;
              const int row0 = brow + wm * 128 + mh * 64 + i * 16 + lq * 4;
              if (wr) {
                  float bvv = 0.0f;
                  if (BIASMODE == 1) bvv = bias[gc];
                  if (BIASMODE == 3) bvv = bias[(long long)bz * 512 + gc];
                  if (ROUTE == 2 && gc < 1024) {
                      // direct v2T write: v2T[(m>>9)*1024+gc][m&511]
                      const int b_ = row0 >> 9, s_ = row0 & 511;
                      bf16 t4[4];
                      #pragma unroll
                      for (int rr = 0; rr < 4; ++rr) {
                          float vv = acc[mh][nh][i][j][rr] + bvv;
                          t4[rr] = (bf16)vv;
                      }
                      *(ushort4*)&((bf16*)Cbase)[((long long)b_ * 1024 + gc) * 512 + s_]
                          = *(ushort4*)t4;
                  } else {
                      long long base; int lc, ld;
                      if (ROUTE == 2) { base = segStride; lc = gc - 1024; ld = 1088; }
                      else { base = cofs0; lc = gc; ld = ldc; }
                      #pragma unroll
                      for (int rr = 0; rr < 4; ++rr) {
                          float vv = acc[mh][nh][i][j][rr] + bvv;
                          if (ACT) vv = vv > 0.0f ? vv : 0.2f * vv;
                          const long long cidx = base + (long long)(row0 + rr) * ld + lc;
                          if (OUT_BF16) ((bf16*)Cbase)[cidx] = (bf16)vv;
                          else          ((float*)Cbase)[cidx] = vv;
                      }
                  }
              }
          }
}

// ---------------------------------------------------------------------------
// gemm256: thin wrapper with XCD-bijective swizzle (T1/m204)
// ---------------------------------------------------------------------------
template<int OUT_BF16, int ACT, int BIASMODE, int ROUTE>
__global__ __launch_bounds__(512, 2)
void gemm256(const bf16* __restrict__ Abase, const bf16* __restrict__ Bbase,
             void* __restrict__ Cbase, const float* __restrict__ bias,
             int K, int lda, int ldb, int ldc, int nwrite,
             long long sA, long long sB, long long sC, long long segStride)
{
    __shared__ bf16 lds[4][8192];   // 64 KiB -> 2 blocks/CU
    const int gx = gridDim.x, gy = gridDim.y;
    const int nwg = gx * gy * gridDim.z;
    const int lin = blockIdx.x + gx * (blockIdx.y + gy * blockIdx.z);
    const int qch = nwg >> 3, rch = nwg & 7;
    const int xcd = lin & 7, pos = lin >> 3;
    const int nl = (xcd < rch ? xcd * (qch + 1)
                              : rch * (qch + 1) + (xcd - rch) * qch) + pos;
    const int bz = nl / (gx * gy);
    const int rem = nl - bz * (gx * gy);
    const int by = rem / gx;
    const int bx = rem - by * gx;
    gemm_core<OUT_BF16, ACT, BIASMODE, ROUTE>(
        &lds[0][0], Abase, Bbase, Cbase, bias, K, lda, ldb, ldc, nwrite,
        sA, sB, sC, segStride, bx, by, bz);
}

// ---------------------------------------------------------------------------
// mega0: heterogeneous dispatch overlapping the two weight GEMMs with
// concat + uvec + biasprep + bvw2.
// blocks [0,25): MT = Wk@Wq^T -> Bqv rows 1024.. ; [25,45): Wv2T -> Bqv 0..1023
// [45,16429): concat 2 rows/block; [16429,16565): uvec; [16565,16568): b1p;
// [16568,16584): bvw2.
// ---------------------------------------------------------------------------
__global__ __launch_bounds__(512, 2)
void mega0_kernel(const float* __restrict__ x, const float* __restrict__ emb,
                  const bf16* __restrict__ wkC, const bf16* __restrict__ wqC,
                  const bf16* __restrict__ w2T, const bf16* __restrict__ wvC,
                  bf16* __restrict__ Bqv, bf16* __restrict__ hcat,
                  const float* __restrict__ wk, const float* __restrict__ bq,
                  float* __restrict__ uvec,
                  const float* __restrict__ b1, float* __restrict__ b1p,
                  const float* __restrict__ bv, const float* __restrict__ w2,
                  const float* __restrict__ b2, float* __restrict__ b2p2)
{
    __shared__ bf16 lds[4][8192];
    const int lin = blockIdx.x;
    const int tid = threadIdx.x;
    if (lin < 25) {
        gemm_core<1, 0, 0, 0>(&lds[0][0], wkC, wqC, Bqv + 1024LL * 1088, nullptr,
                              1088, 1088, 1088, 1088, 1088, 0, 0, 0, 0,
                              lin % 5, lin / 5, 0);
    } else if (lin < 45) {
        const int l = lin - 25;
        gemm_core<1, 0, 0, 0>(&lds[0][0], w2T, wvC, Bqv, nullptr,
                              1088, 1088, 1088, 1088, 1088, 0, 0, 0, 0,
                              l % 5, l / 5, 0);
    } else if (lin < 16429) {
        // concat(x, emb) -> hcat [32768][1088]; 2 rows per block
        const int m = (lin - 45) * 2 + (tid >> 8);
        const int t = tid & 255;
        const int s = m & 511;
        const float* xr = x + (long long)m * 1024;
        bf16* orow = hcat + (long long)m * 1088;
        for (int g = t; g < 272; g += 256) {
            const int c = g * 4;
            float4 v;
            if (c < 1024)      v = *(const float4*)&xr[c];
            else if (c < 1056) v = *(const float4*)&emb[s * 32 + (c - 1024)];
            else               v = make_float4(0.f, 0.f, 0.f, 0.f);
            bf16 tt[4] = { (bf16)v.x, (bf16)v.y, (bf16)v.z, (bf16)v.w };
            *(ushort4*)&orow[c] = *(ushort4*)tt;
        }
    } else if (lin < 16565) {
        // uvec: u[e] = wk[e][:] . bq ; 8 e per block (8 waves)
        const int wid = tid >> 6, lane = tid & 63;
        const int e = (lin - 16429) * 8 + wid;
        if (e < 1088) {
            float s = 0.0f;
            if (e < 1056) {
                for (int d = lane; d < 1056; d += 64)
                    s += wk[(long long)e * 1056 + d] * bq[d];
            }
            #pragma unroll
            for (int sh = 32; sh > 0; sh >>= 1) s += __shfl_xor(s, sh);
            if (lane == 0) uvec[e] = s;
        }
    } else if (lin < 16568) {
        const int i = (lin - 16565) * 512 + tid;
        if (i < 1088) b1p[i] = (i < 1056) ? b1[i] : 0.0f;
    } else {
        // bvw2: b2p2[n] = b2[n] + bv . w2[:,n] ; 64 n per block, o split 8-way
        const int l = lin - 16568;
        const int nn = l * 64 + (tid & 63), oq = tid >> 6;
        float s = 0.0f;
        for (int o = oq; o < 1056; o += 8)
            s += bv[o] * w2[(long long)o * 1024 + nn];
        float* red = (float*)&lds[0][0];
        red[tid] = s;
        __syncthreads();
        if (tid < 64) {
            float t2 = b2[l * 64 + tid];
            #pragma unroll
            for (int q = 0; q < 8; ++q) t2 += red[q * 64 + tid];
            b2p2[l * 64 + tid] = t2;
        }
    }
}

// ---------------------------------------------------------------------------
// weight prep: z=0 w1->w1T[1280][1088] (transpose); z=1 wv->wvC pad-cast;
// z=2 w2->w2T[1024][1088] (transpose); z=3 wq->wqC pad-cast; z=4 wk->wkC.
// ---------------------------------------------------------------------------
__global__ void wprep_kernel(const float* __restrict__ w1, const float* __restrict__ wv,
                             const float* __restrict__ w2, const float* __restrict__ wq,
                             const float* __restrict__ wk,
                             bf16* __restrict__ w1T, bf16* __restrict__ wvC,
                             bf16* __restrict__ w2T, bf16* __restrict__ wqC,
                             bf16* __restrict__ wkC)
{
    const int z = blockIdx.z;
    const int tx = threadIdx.x, ty = threadIdx.y;
    if (z == 1 || z >= 3) {   // pad-cast, no transpose: dst [1280][1088]
        const float* src = (z == 1) ? wv : (z == 3) ? wq : wk;
        bf16* dst = (z == 1) ? wvC : (z == 3) ? wqC : wkC;
        const int r = blockIdx.y * 32 + ty, c = blockIdx.x * 32 + tx;
        if (r < 1280 && c < 1088) {
            float v = (r < 1056 && c < 1056) ? src[(long long)r * 1056 + c] : 0.0f;
            dst[(long long)r * 1088 + c] = (bf16)v;
        }
        return;
    }
    const float* src; bf16* dst; int NIN, NP, srcld;
    if (z == 0) { src = w1; dst = w1T; NIN = 1056; NP = 1280; srcld = 1056; }
    else        { src = w2; dst = w2T; NIN = 1024; NP = 1024; srcld = 1024; }
    const int KIN = 1056, KP = 1088;
    const int k0 = blockIdx.x * 32, n0 = blockIdx.y * 32;
    if (n0 >= NP) return;
    __shared__ float t[32][33];
    const int kk = k0 + ty, nn = n0 + tx;
    t[ty][tx] = (kk < KIN && nn < NIN) ? src[(long long)kk * srcld + nn] : 0.0f;
    __syncthreads();
    const int ko = k0 + tx, no = n0 + ty;
    if (no < NP && ko < KP)
        dst[(long long)no * KP + ko] = (bf16)t[tx][ty];
}

// ---------------------------------------------------------------------------
// c[m] = dot(h[m][0..1087], u); dynamic skip when u == 0 (bq == 0 case)
// ---------------------------------------------------------------------------
__global__ __launch_bounds__(256)
void cvec_kernel(const bf16* __restrict__ h, const float* __restrict__ u,
                 float* __restrict__ c)
{
    __shared__ float sred[256];
    __shared__ int nz;
    const int tid = threadIdx.x;
    float su = 0.0f;
    for (int i = tid; i < 1088; i += 256) su += fabsf(u[i]);
    sred[tid] = su;
    __syncthreads();
    if (tid < 128) sred[tid] += sred[tid + 128];
    __syncthreads();
    if (tid < 64) sred[tid] += sred[tid + 64];
    __syncthreads();
    if (tid == 0) {
        float t = 0.0f;
        for (int i = 0; i < 64; ++i) t += sred[i];
        nz = (t != 0.0f);
    }
    __syncthreads();
    const int wid = tid >> 6, lane = tid & 63;
    const long long row = (long long)blockIdx.x * 4 + wid;
    if (!nz) {
        if (lane == 0) c[row] = 0.0f;
        return;
    }
    const bf16* hr = h + row * 1088;
    float s = 0.0f;
    #pragma unroll
    for (int j = 0; j < 17; ++j)
        s += (float)hr[j * 64 + lane] * u[j * 64 + lane];
    #pragma unroll
    for (int sh = 32; sh > 0; sh >>= 1) s += __shfl_xor(s, sh);
    if (lane == 0) c[row] = s;
}

// ---------------------------------------------------------------------------
// row softmax: energy f32 [32768,512] -> attn bf16 [32768,512]; 1 wave/row
// ---------------------------------------------------------------------------
__global__ __launch_bounds__(256)
void softmax_kernel(const float* __restrict__ e, bf16* __restrict__ p)
{
    const int wid = threadIdx.x >> 6, lane = threadIdx.x & 63;
    const long long row = (long long)blockIdx.x * 4 + wid;
    const float* er = e + row * 512;
    float v[8];
    float mx = -3.0e38f;
    #pragma unroll
    for (int j = 0; j < 8; ++j) { v[j] = er[j * 64 + lane]; mx = fmaxf(mx, v[j]); }
    #pragma unroll
    for (int s = 32; s > 0; s >>= 1) mx = fmaxf(mx, __shfl_xor(mx, s));
    float sum = 0.0f;
    #pragma unroll
    for (int j = 0; j < 8; ++j) { v[j] = __expf(v[j] - mx); sum += v[j]; }
    #pragma unroll
    for (int s = 32; s > 0; s >>= 1) sum += __shfl_xor(sum, s);
    const float inv = 1.0f / sum;
    bf16* pr = p + row * 512;
    #pragma unroll
    for (int j = 0; j < 8; ++j) pr[j * 64 + lane] = (bf16)(v[j] * inv);
}

// ---------------------------------------------------------------------------
extern "C" void kernel_launch(void* const* d_in, const int* in_sizes, int n_in,
                              void* d_out, int out_size, void* d_ws, size_t ws_size,
                              hipStream_t stream)
{
    const float* x   = (const float*)d_in[0];
    const float* emb = (const float*)d_in[1];
    const float* w1  = (const float*)d_in[2];
    const float* b1  = (const float*)d_in[3];
    const float* wq  = (const float*)d_in[4];
    const float* bq  = (const float*)d_in[5];
    const float* wk  = (const float*)d_in[6];
    // const float* bk = (const float*)d_in[7];  // drops under softmax shift
    const float* wv  = (const float*)d_in[8];
    const float* bv  = (const float*)d_in[9];
    const float* w2  = (const float*)d_in[10];
    const float* b2  = (const float*)d_in[11];
    float* out = (float*)d_out;

    const long long Mrows = 32768;   // 64 * 512
    const int KR = 1088;             // compute K (17*64 >= 1056)

    char* ws = (char*)d_ws;
    size_t off = 0;
    auto alloc = [&](size_t bytes) -> char* {
        char* p = ws + off;
        off += (bytes + 255) & ~(size_t)255;
        return p;
    };
    char* R1   = alloc((size_t)Mrows * KR * 2);          // hcat -> energy
    char* Rh   = alloc((size_t)Mrows * KR * 2);          // h (lives to energy)
    char* Rq   = alloc((size_t)Mrows * KR * 2);          // q' -> attn
    bf16* v2T  = (bf16*)alloc((size_t)64 * 1024 * 512 * 2);
    bf16* w1T  = (bf16*)alloc((size_t)1280 * KR * 2);
    bf16* Bqv  = (bf16*)alloc((size_t)2304 * KR * 2);    // [0..1023]=Wv2T, [1024..]=M^T
    bf16* w2T  = (bf16*)alloc((size_t)1024 * KR * 2);
    bf16* wqC  = (bf16*)alloc((size_t)1280 * KR * 2);
    bf16* wkC  = (bf16*)alloc((size_t)1280 * KR * 2);
    bf16* wvC  = (bf16*)alloc((size_t)1280 * KR * 2);
    float* b1p  = (float*)alloc((size_t)1088 * 4);
    float* b2p2 = (float*)alloc((size_t)1024 * 4);
    float* uvec = (float*)alloc((size_t)1088 * 4);
    float* cvec = (float*)alloc((size_t)Mrows * 4);

    bf16*  hcat   = (bf16*)R1;
    float* energy = (float*)R1;       // after l1 consumed hcat (67<=71MB)
    bf16*  h      = (bf16*)Rh;        // [32768][1088], alive until energy
    bf16*  qbuf   = (bf16*)Rq;        // q' [32768][1088]
    bf16*  attn   = (bf16*)Rq;        // after energy consumed q'

    // 1. weight transpose/cast prep
    wprep_kernel<<<dim3(34, 40, 5), dim3(32, 32), 0, stream>>>(
        w1, wv, w2, wq, wk, w1T, wvC, w2T, wqC, wkC);
    // 2. mega0: {MT, Wv2T} GEMMs || concat || uvec || b1p || bvw2
    mega0_kernel<<<16584, 512, 0, stream>>>(
        x, emb, wkC, wqC, w2T, wvC, Bqv, hcat,
        wk, bq, uvec, b1, b1p, bv, w2, b2, b2p2);
    // 3. h = leaky_relu(hcat @ w1^T + b1)   M=32768 Ngrid=1280 K=1088
    gemm256<1, 1, 1, 0><<<dim3(5, 128, 1), 512, 0, stream>>>(
        hcat, w1T, h, b1p, KR, KR, KR, KR, KR, 0, 0, 0, 0);
    // 4. c[m] = h[m] . u  (skips h read when u == 0)
    cvec_kernel<<<8192, 256, 0, stream>>>(h, uvec, cvec);
    // 5. v2(->v2T direct) | q' = h @ Bqv^T   M=32768 Ngrid=2304 K=1088
    gemm256<1, 0, 0, 2><<<dim3(9, 128, 1), 512, 0, stream>>>(
        h, Bqv, v2T, nullptr, KR, KR, KR, 0, 2112, 0, 0, 0,
        (long long)(qbuf - v2T));
    // 6. energy[b] = q'_b @ h_b^T + c[t]  (f32, into dead hcat region)
    gemm256<0, 0, 3, 0><<<dim3(2, 2, 64), 512, 0, stream>>>(
        qbuf, h, energy, cvec, KR, KR, KR, 512, 512,
        512LL * KR, 512LL * KR, 512LL * 512, 0);
    // 7. softmax rows -> bf16 (into dead q' region)
    softmax_kernel<<<8192, 256, 0, stream>>>(energy, attn);
    // 8. out[b] = attn_b @ v2_b + (bv@W2 + b2)   f32 final output
    gemm256<0, 0, 1, 0><<<dim3(4, 2, 64), 512, 0, stream>>>(
        attn, v2T, out, b2p2, 512, 512, 512, 1024, 1024,
        512LL * 512, 1024LL * 512, 512LL * 1024, 0);
}

// Round 15
// 586.210 us; speedup vs baseline: 1.0712x; 1.0712x over previous
//
#include <hip/hip_runtime.h>
#include <hip/hip_bf16.h>
#include <cstdint>

typedef __hip_bfloat16 bf16;
typedef __attribute__((ext_vector_type(8))) short short8;
typedef __attribute__((ext_vector_type(4))) float f32x4;

// ---------------------------------------------------------------------------
// async global->LDS, 16B/lane (wave-uniform LDS base + lane*16 implicit)
// ---------------------------------------------------------------------------
__device__ __forceinline__ void gload16(const bf16* g, bf16* l) {
    __builtin_amdgcn_global_load_lds(
        (__attribute__((address_space(1))) void*)g,
        (__attribute__((address_space(3))) void*)l, 16, 0, 0);
}
#define VMC(n) asm volatile("s_waitcnt vmcnt(" #n ")" ::: "memory")
__device__ __forceinline__ void bar() {
    asm volatile("" ::: "memory");
    __builtin_amdgcn_s_barrier();
    asm volatile("" ::: "memory");
}

// ---------------------------------------------------------------------------
// stage one half-tile [128 rows x 64 cols bf16] into a linear LDS region.
// Source pre-swizzled: LDS(r, slot) = G(r, slot ^ (r&7)) [16B slots].
// ---------------------------------------------------------------------------
__device__ __forceinline__ void stage_half(const bf16* __restrict__ G, int ld,
                                           int row0, int k0, bf16* lregion,
                                           int w, int lrow, int lslot)
{
    const bf16* s0 = G + (long long)(row0 + w * 8 + lrow) * ld + (k0 + lslot * 8);
    gload16(s0, lregion + (w * 64) * 8);
    gload16(s0 + (long long)64 * ld, lregion + (512 + w * 64) * 8);
}

// round-7 lesson: each wave reads ONLY its own region (buf,op=A,half=wm); any
// fragment read of tile t requires BOTH A stages of t drained.
#define LOAD_AI(dst, i_, mh, P) do { \
    _Pragma("unroll") for (int ks_ = 0; ks_ < 2; ++ks_) \
      dst[i_][ks_] = *(const short8*)((P) + ((mh) * 64 + (i_) * 16 + l15) * 64 \
                                         + (((ks_ * 4 + lq) ^ l7) * 8)); } while (0)
#define LOAD_B(nh, dst) do { _Pragma("unroll") for (int j_ = 0; j_ < 2; ++j_) { \
    _Pragma("unroll") for (int ks_ = 0; ks_ < 2; ++ks_) \
      dst[j_][ks_] = *(const short8*)(pb + (bhr + (nh) * 32 + j_ * 16 + l15) * 64 \
                                         + (((ks_ * 4 + lq) ^ l7) * 8)); } } while (0)
#define DO_Q(mh, nh, AF, BF) do { \
    __builtin_amdgcn_s_setprio(1); \
    _Pragma("unroll") for (int i_ = 0; i_ < 4; ++i_) \
      _Pragma("unroll") for (int j_ = 0; j_ < 2; ++j_) \
        _Pragma("unroll") for (int ks_ = 0; ks_ < 2; ++ks_) \
          acc[mh][nh][i_][j_] = __builtin_amdgcn_mfma_f32_16x16x32_bf16( \
              AF[i_][ks_], BF[j_][ks_], acc[mh][nh][i_][j_], 0, 0, 0); \
    __builtin_amdgcn_s_setprio(0); \
} while (0)

// ---------------------------------------------------------------------------
// 256x256 8-phase bf16 GEMM core (r13 proven form), C = A*B^T (+bias)(+act).
// LDS 128 KiB: region(buf,op,half) = ldsb + ((buf*2+op)*2+half)*8192.
// BIASMODE: 0 none; 1 bias[gc]; 3 bias[bz*512+gc] (energy c[t] term).
// ROUTE: 0 single output; 2 dual (gc<1024 -> v2T direct; else q' ld 1088).
// ---------------------------------------------------------------------------
template<int OUT_BF16, int ACT, int BIASMODE, int ROUTE>
__device__ __forceinline__ void gemm_core(
    bf16* ldsb,
    const bf16* __restrict__ Abase, const bf16* __restrict__ Bbase,
    void* __restrict__ Cbase, const float* __restrict__ bias,
    int K, int lda, int ldb, int ldc, int nwrite,
    long long sA, long long sB, long long sC, long long segStride,
    int bx, int by, int bz)
{
    const int tid = threadIdx.x;
    const int wid = tid >> 6, lane = tid & 63;
    const int wm = wid >> 2, wn = wid & 3;          // 2 x 4 waves
    const int l15 = lane & 15, l7 = lane & 7, lq = lane >> 4;
    const int lrow = lane >> 3, lslot = l7 ^ lrow;  // staging per-lane geom
    const int bhr = (wn & 1) * 64;                  // B row base within half

    const bf16* A = Abase + (long long)bz * sA;
    const bf16* B = Bbase + (long long)bz * sB;
    const int brow = by * 256, bcol = bx * 256;

    f32x4 acc[2][2][4][2] = {};
    short8 aFe[4][2], aFo[4][2], bF0[2][2], bF1[2][2];

    const int nt = K >> 6;

    // ---- prologue: t0.B, t0.A -> buf0 ; t1.B -> buf1 ----
    stage_half(B, ldb, bcol,       0,  ldsb + 2 * 8192, wid, lrow, lslot);
    stage_half(B, ldb, bcol + 128, 0,  ldsb + 3 * 8192, wid, lrow, lslot);
    stage_half(A, lda, brow,       0,  ldsb,            wid, lrow, lslot);
    stage_half(A, lda, brow + 128, 0,  ldsb + 1 * 8192, wid, lrow, lslot);
    stage_half(B, ldb, bcol,       64, ldsb + 6 * 8192, wid, lrow, lslot);
    stage_half(B, ldb, bcol + 128, 64, ldsb + 7 * 8192, wid, lrow, lslot);
    VMC(4);   // drain B(0)+A(0); leaves B0(1),B1(1) = 4 (steady-state entry)
    bar();

    for (int t = 0; t < nt; ++t) {
        const int b = t & 1;
        const bf16* pa = ldsb + (b * 4 + wm) * 8192;
        const bf16* pb = ldsb + (b * 4 + 2 + (wn >> 1)) * 8192;
        bf16* oA = ldsb + ((b ^ 1) * 4) * 8192;   // next tile's A -> other buf
        bf16* cB = ldsb + (b * 4 + 2) * 8192;     // tile t+2's B -> current buf
        const int t1 = (t + 1 == nt) ? 0 : t + 1;
        const int t2 = (t + 2 >= nt) ? t + 2 - nt : t + 2;
        const int k1 = t1 << 6, k2 = t2 << 6;

        // ---- p1: read aFe + both B halves; stage A0(t+1); Q(0,0) ----
        LOAD_B(0, bF0);
        LOAD_AI(aFe, 0, 0, pa); LOAD_AI(aFe, 1, 0, pa);
        LOAD_AI(aFe, 2, 0, pa); LOAD_AI(aFe, 3, 0, pa);
        LOAD_B(1, bF1);
        stage_half(A, lda, brow, k1, oA, wid, lrow, lslot);
        bar();
        DO_Q(0, 0, aFe, bF0);
        bar();

        // ---- p2: read aFo[0,1]; stage A1(t+1); Q(0,1) ----
        LOAD_AI(aFo, 0, 1, pa); LOAD_AI(aFo, 1, 1, pa);
        stage_half(A, lda, brow + 128, k1, oA + 8192, wid, lrow, lslot);
        bar();
        DO_Q(0, 1, aFe, bF1);
        bar();

        // ---- p3: read aFo[2,3]; stage B0(t+2); Q(1,1) ----
        LOAD_AI(aFo, 2, 1, pa); LOAD_AI(aFo, 3, 1, pa);
        stage_half(B, ldb, bcol, k2, cB, wid, lrow, lslot);
        bar();
        DO_Q(1, 1, aFo, bF1);
        bar();

        // ---- p4: stage B1(t+2); Q(1,0); tile-boundary drain ----
        stage_half(B, ldb, bcol + 128, k2, cB + 8192, wid, lrow, lslot);
        bar();
        DO_Q(1, 0, aFo, bF0);
        VMC(4);   // drain B(t+1)+A(t+1); B(t+2) pair stays in flight
        bar();
    }
    VMC(0);   // drain wrapped stray stages

    // ---- epilogue: C/D layout col = lane&15, row = (lane>>4)*4 + rr ----
    const long long cofs0 = (long long)bz * sC;
    #pragma unroll
    for (int mh = 0; mh < 2; ++mh)
      #pragma unroll
      for (int nh = 0; nh < 2; ++nh)
        #pragma unroll
        for (int i = 0; i < 4; ++i)
          #pragma unroll
          for (int j = 0; j < 2; ++j) {
              const int gc = bcol + wn * 64 + nh * 32 + j * 16 + l15;
              const bool wr = gc < nwrite;
              const int row0 = brow + wm * 128 + mh * 64 + i * 16 + lq * 4;
              if (wr) {
                  float bvv = 0.0f;
                  if (BIASMODE == 1) bvv = bias[gc];
                  if (BIASMODE == 3) bvv = bias[(long long)bz * 512 + gc];
                  if (ROUTE == 2 && gc < 1024) {
                      // direct v2T write: v2T[(m>>9)*1024+gc][m&511]
                      const int b_ = row0 >> 9, s_ = row0 & 511;
                      bf16 t4[4];
                      #pragma unroll
                      for (int rr = 0; rr < 4; ++rr) {
                          float vv = acc[mh][nh][i][j][rr] + bvv;
                          t4[rr] = (bf16)vv;
                      }
                      *(ushort4*)&((bf16*)Cbase)[((long long)b_ * 1024 + gc) * 512 + s_]
                          = *(ushort4*)t4;
                  } else {
                      long long base; int lc, ld;
                      if (ROUTE == 2) { base = segStride; lc = gc - 1024; ld = 1088; }
                      else { base = cofs0; lc = gc; ld = ldc; }
                      #pragma unroll
                      for (int rr = 0; rr < 4; ++rr) {
                          float vv = acc[mh][nh][i][j][rr] + bvv;
                          if (ACT) vv = vv > 0.0f ? vv : 0.2f * vv;
                          const long long cidx = base + (long long)(row0 + rr) * ld + lc;
                          if (OUT_BF16) ((bf16*)Cbase)[cidx] = (bf16)vv;
                          else          ((float*)Cbase)[cidx] = vv;
                      }
                  }
              }
          }
}

// ---------------------------------------------------------------------------
// gemm256: thin wrapper with XCD-bijective swizzle (T1/m204)
// ---------------------------------------------------------------------------
template<int OUT_BF16, int ACT, int BIASMODE, int ROUTE>
__global__ __launch_bounds__(512, 2)
void gemm256(const bf16* __restrict__ Abase, const bf16* __restrict__ Bbase,
             void* __restrict__ Cbase, const float* __restrict__ bias,
             int K, int lda, int ldb, int ldc, int nwrite,
             long long sA, long long sB, long long sC, long long segStride)
{
    __shared__ bf16 lds[8][8192];
    const int gx = gridDim.x, gy = gridDim.y;
    const int nwg = gx * gy * gridDim.z;
    const int lin = blockIdx.x + gx * (blockIdx.y + gy * blockIdx.z);
    const int qch = nwg >> 3, rch = nwg & 7;
    const int xcd = lin & 7, pos = lin >> 3;
    const int nl = (xcd < rch ? xcd * (qch + 1)
                              : rch * (qch + 1) + (xcd - rch) * qch) + pos;
    const int bz = nl / (gx * gy);
    const int rem = nl - bz * (gx * gy);
    const int by = rem / gx;
    const int bx = rem - by * gx;
    gemm_core<OUT_BF16, ACT, BIASMODE, ROUTE>(
        &lds[0][0], Abase, Bbase, Cbase, bias, K, lda, ldb, ldc, nwrite,
        sA, sB, sC, segStride, bx, by, bz);
}

// ---------------------------------------------------------------------------
// qv + cvec fused dispatch: blocks [0,1152) = qv GEMM (swizzled over 1152);
// blocks [1152,1664) = cvec, 64 rows each (8 waves x 8 rows).
// ---------------------------------------------------------------------------
__global__ __launch_bounds__(512, 2)
void qv_cvec_kernel(const bf16* __restrict__ h, const bf16* __restrict__ Bqv,
                    bf16* __restrict__ v2T, long long qOffset,
                    const float* __restrict__ uvec, float* __restrict__ cvec)
{
    __shared__ bf16 lds[8][8192];
    const int lin = blockIdx.x;
    const int tid = threadIdx.x;
    if (lin < 1152) {
        // XCD-bijective swizzle over the 1152 GEMM blocks (gx=9, gy=128)
        const int qch = 1152 >> 3;           // 144, rch = 0
        const int xcd = lin & 7, pos = lin >> 3;
        const int nl = xcd * qch + pos;
        const int by = nl / 9;
        const int bx = nl - by * 9;
        gemm_core<1, 0, 0, 2>(&lds[0][0], h, Bqv, v2T, nullptr,
                              1088, 1088, 1088, 0, 2112, 0, 0, 0, qOffset,
                              bx, by, 0);
        return;
    }
    // ---- cvec branch: c[m] = h[m] . u, dynamic skip when u == 0 ----
    const int cblk = lin - 1152;             // 0..511, 64 rows each
    float* red = (float*)&lds[0][0];
    __shared__ int nz;
    float su = 0.0f;
    for (int i = tid; i < 1088; i += 512) su += fabsf(uvec[i]);
    red[tid] = su;
    __syncthreads();
    if (tid < 256) red[tid] += red[tid + 256];
    __syncthreads();
    if (tid < 128) red[tid] += red[tid + 128];
    __syncthreads();
    if (tid == 0) {
        float t = 0.0f;
        for (int i = 0; i < 128; ++i) t += red[i];
        nz = (t != 0.0f);
    }
    __syncthreads();
    if (!nz) {
        if (tid < 64) cvec[(long long)cblk * 64 + tid] = 0.0f;
        return;
    }
    const int wid = tid >> 6, lane = tid & 63;
    for (int it = 0; it < 8; ++it) {
        const long long row = (long long)cblk * 64 + it * 8 + wid;
        const bf16* hr = h + row * 1088;
        float s = 0.0f;
        #pragma unroll
        for (int j = 0; j < 17; ++j)
            s += (float)hr[j * 64 + lane] * uvec[j * 64 + lane];
        #pragma unroll
        for (int sh = 32; sh > 0; sh >>= 1) s += __shfl_xor(s, sh);
        if (lane == 0) cvec[row] = s;
    }
}

// ---------------------------------------------------------------------------
// mega0: heterogeneous dispatch overlapping the two weight GEMMs with
// concat + uvec + biasprep + bvw2.
// blocks [0,25): MT = Wk@Wq^T -> Bqv rows 1024.. ; [25,45): Wv2T -> Bqv 0..1023
// [45,16429): concat 2 rows/block; [16429,16565): uvec; [16565,16568): b1p;
// [16568,16584): bvw2.
// ---------------------------------------------------------------------------
__global__ __launch_bounds__(512, 2)
void mega0_kernel(const float* __restrict__ x, const float* __restrict__ emb,
                  const bf16* __restrict__ wkC, const bf16* __restrict__ wqC,
                  const bf16* __restrict__ w2T, const bf16* __restrict__ wvC,
                  bf16* __restrict__ Bqv, bf16* __restrict__ hcat,
                  const float* __restrict__ wk, const float* __restrict__ bq,
                  float* __restrict__ uvec,
                  const float* __restrict__ b1, float* __restrict__ b1p,
                  const float* __restrict__ bv, const float* __restrict__ w2,
                  const float* __restrict__ b2, float* __restrict__ b2p2)
{
    __shared__ bf16 lds[8][8192];
    const int lin = blockIdx.x;
    const int tid = threadIdx.x;
    if (lin < 25) {
        gemm_core<1, 0, 0, 0>(&lds[0][0], wkC, wqC, Bqv + 1024LL * 1088, nullptr,
                              1088, 1088, 1088, 1088, 1088, 0, 0, 0, 0,
                              lin % 5, lin / 5, 0);
    } else if (lin < 45) {
        const int l = lin - 25;
        gemm_core<1, 0, 0, 0>(&lds[0][0], w2T, wvC, Bqv, nullptr,
                              1088, 1088, 1088, 1088, 1088, 0, 0, 0, 0,
                              l % 5, l / 5, 0);
    } else if (lin < 16429) {
        // concat(x, emb) -> hcat [32768][1088]; 2 rows per block
        const int m = (lin - 45) * 2 + (tid >> 8);
        const int t = tid & 255;
        const int s = m & 511;
        const float* xr = x + (long long)m * 1024;
        bf16* orow = hcat + (long long)m * 1088;
        for (int g = t; g < 272; g += 256) {
            const int c = g * 4;
            float4 v;
            if (c < 1024)      v = *(const float4*)&xr[c];
            else if (c < 1056) v = *(const float4*)&emb[s * 32 + (c - 1024)];
            else               v = make_float4(0.f, 0.f, 0.f, 0.f);
            bf16 tt[4] = { (bf16)v.x, (bf16)v.y, (bf16)v.z, (bf16)v.w };
            *(ushort4*)&orow[c] = *(ushort4*)tt;
        }
    } else if (lin < 16565) {
        // uvec: u[e] = wk[e][:] . bq ; 8 e per block (8 waves)
        const int wid = tid >> 6, lane = tid & 63;
        const int e = (lin - 16429) * 8 + wid;
        if (e < 1088) {
            float s = 0.0f;
            if (e < 1056) {
                for (int d = lane; d < 1056; d += 64)
                    s += wk[(long long)e * 1056 + d] * bq[d];
            }
            #pragma unroll
            for (int sh = 32; sh > 0; sh >>= 1) s += __shfl_xor(s, sh);
            if (lane == 0) uvec[e] = s;
        }
    } else if (lin < 16568) {
        const int i = (lin - 16565) * 512 + tid;
        if (i < 1088) b1p[i] = (i < 1056) ? b1[i] : 0.0f;
    } else {
        // bvw2: b2p2[n] = b2[n] + bv . w2[:,n] ; 64 n per block, o split 8-way
        const int l = lin - 16568;
        const int nn = l * 64 + (tid & 63), oq = tid >> 6;
        float s = 0.0f;
        for (int o = oq; o < 1056; o += 8)
            s += bv[o] * w2[(long long)o * 1024 + nn];
        float* red = (float*)&lds[0][0];
        red[tid] = s;
        __syncthreads();
        if (tid < 64) {
            float t2 = b2[l * 64 + tid];
            #pragma unroll
            for (int q = 0; q < 8; ++q) t2 += red[q * 64 + tid];
            b2p2[l * 64 + tid] = t2;
        }
    }
}

// ---------------------------------------------------------------------------
// weight prep: z=0 w1->w1T[1280][1088] (transpose); z=1 wv->wvC pad-cast;
// z=2 w2->w2T[1024][1088] (transpose); z=3 wq->wqC pad-cast; z=4 wk->wkC.
// ---------------------------------------------------------------------------
__global__ void wprep_kernel(const float* __restrict__ w1, const float* __restrict__ wv,
                             const float* __restrict__ w2, const float* __restrict__ wq,
                             const float* __restrict__ wk,
                             bf16* __restrict__ w1T, bf16* __restrict__ wvC,
                             bf16* __restrict__ w2T, bf16* __restrict__ wqC,
                             bf16* __restrict__ wkC)
{
    const int z = blockIdx.z;
    const int tx = threadIdx.x, ty = threadIdx.y;
    if (z == 1 || z >= 3) {   // pad-cast, no transpose: dst [1280][1088]
        const float* src = (z == 1) ? wv : (z == 3) ? wq : wk;
        bf16* dst = (z == 1) ? wvC : (z == 3) ? wqC : wkC;
        const int r = blockIdx.y * 32 + ty, c = blockIdx.x * 32 + tx;
        if (r < 1280 && c < 1088) {
            float v = (r < 1056 && c < 1056) ? src[(long long)r * 1056 + c] : 0.0f;
            dst[(long long)r * 1088 + c] = (bf16)v;
        }
        return;
    }
    const float* src; bf16* dst; int NIN, NP, srcld;
    if (z == 0) { src = w1; dst = w1T; NIN = 1056; NP = 1280; srcld = 1056; }
    else        { src = w2; dst = w2T; NIN = 1024; NP = 1024; srcld = 1024; }
    const int KIN = 1056, KP = 1088;
    const int k0 = blockIdx.x * 32, n0 = blockIdx.y * 32;
    if (n0 >= NP) return;
    __shared__ float t[32][33];
    const int kk = k0 + ty, nn = n0 + tx;
    t[ty][tx] = (kk < KIN && nn < NIN) ? src[(long long)kk * srcld + nn] : 0.0f;
    __syncthreads();
    const int ko = k0 + tx, no = n0 + ty;
    if (no < NP && ko < KP)
        dst[(long long)no * KP + ko] = (bf16)t[tx][ty];
}

// ---------------------------------------------------------------------------
// row softmax: energy f32 [32768,512] -> attn bf16 [32768,512]; 1 wave/row
// ---------------------------------------------------------------------------
__global__ __launch_bounds__(256)
void softmax_kernel(const float* __restrict__ e, bf16* __restrict__ p)
{
    const int wid = threadIdx.x >> 6, lane = threadIdx.x & 63;
    const long long row = (long long)blockIdx.x * 4 + wid;
    const float* er = e + row * 512;
    float v[8];
    float mx = -3.0e38f;
    #pragma unroll
    for (int j = 0; j < 8; ++j) { v[j] = er[j * 64 + lane]; mx = fmaxf(mx, v[j]); }
    #pragma unroll
    for (int s = 32; s > 0; s >>= 1) mx = fmaxf(mx, __shfl_xor(mx, s));
    float sum = 0.0f;
    #pragma unroll
    for (int j = 0; j < 8; ++j) { v[j] = __expf(v[j] - mx); sum += v[j]; }
    #pragma unroll
    for (int s = 32; s > 0; s >>= 1) sum += __shfl_xor(sum, s);
    const float inv = 1.0f / sum;
    bf16* pr = p + row * 512;
    #pragma unroll
    for (int j = 0; j < 8; ++j) pr[j * 64 + lane] = (bf16)(v[j] * inv);
}

// ---------------------------------------------------------------------------
extern "C" void kernel_launch(void* const* d_in, const int* in_sizes, int n_in,
                              void* d_out, int out_size, void* d_ws, size_t ws_size,
                              hipStream_t stream)
{
    const float* x   = (const float*)d_in[0];
    const float* emb = (const float*)d_in[1];
    const float* w1  = (const float*)d_in[2];
    const float* b1  = (const float*)d_in[3];
    const float* wq  = (const float*)d_in[4];
    const float* bq  = (const float*)d_in[5];
    const float* wk  = (const float*)d_in[6];
    // const float* bk = (const float*)d_in[7];  // drops under softmax shift
    const float* wv  = (const float*)d_in[8];
    const float* bv  = (const float*)d_in[9];
    const float* w2  = (const float*)d_in[10];
    const float* b2  = (const float*)d_in[11];
    float* out = (float*)d_out;

    const long long Mrows = 32768;   // 64 * 512
    const int KR = 1088;             // compute K (17*64 >= 1056)

    char* ws = (char*)d_ws;
    size_t off = 0;
    auto alloc = [&](size_t bytes) -> char* {
        char* p = ws + off;
        off += (bytes + 255) & ~(size_t)255;
        return p;
    };
    char* R1   = alloc((size_t)Mrows * KR * 2);          // hcat -> energy
    char* Rh   = alloc((size_t)Mrows * KR * 2);          // h (lives to energy)
    char* Rq   = alloc((size_t)Mrows * KR * 2);          // q' -> attn
    bf16* v2T  = (bf16*)alloc((size_t)64 * 1024 * 512 * 2);
    bf16* w1T  = (bf16*)alloc((size_t)1280 * KR * 2);
    bf16* Bqv  = (bf16*)alloc((size_t)2304 * KR * 2);    // [0..1023]=Wv2T, [1024..]=M^T
    bf16* w2T  = (bf16*)alloc((size_t)1024 * KR * 2);
    bf16* wqC  = (bf16*)alloc((size_t)1280 * KR * 2);
    bf16* wkC  = (bf16*)alloc((size_t)1280 * KR * 2);
    bf16* wvC  = (bf16*)alloc((size_t)1280 * KR * 2);
    float* b1p  = (float*)alloc((size_t)1088 * 4);
    float* b2p2 = (float*)alloc((size_t)1024 * 4);
    float* uvec = (float*)alloc((size_t)1088 * 4);
    float* cvec = (float*)alloc((size_t)Mrows * 4);

    bf16*  hcat   = (bf16*)R1;
    float* energy = (float*)R1;       // after l1 consumed hcat (67<=71MB)
    bf16*  h      = (bf16*)Rh;        // [32768][1088], alive until energy
    bf16*  qbuf   = (bf16*)Rq;        // q' [32768][1088]
    bf16*  attn   = (bf16*)Rq;        // after energy consumed q'

    // 1. weight transpose/cast prep
    wprep_kernel<<<dim3(34, 40, 5), dim3(32, 32), 0, stream>>>(
        w1, wv, w2, wq, wk, w1T, wvC, w2T, wqC, wkC);
    // 2. mega0: {MT, Wv2T} GEMMs || concat || uvec || b1p || bvw2
    mega0_kernel<<<16584, 512, 0, stream>>>(
        x, emb, wkC, wqC, w2T, wvC, Bqv, hcat,
        wk, bq, uvec, b1, b1p, bv, w2, b2, b2p2);
    // 3. h = leaky_relu(hcat @ w1^T + b1)   M=32768 Ngrid=1280 K=1088
    gemm256<1, 1, 1, 0><<<dim3(5, 128, 1), 512, 0, stream>>>(
        hcat, w1T, h, b1p, KR, KR, KR, KR, KR, 0, 0, 0, 0);
    // 4. qv GEMM (v2->v2T direct | q') + cvec fused tail blocks
    qv_cvec_kernel<<<1664, 512, 0, stream>>>(
        h, Bqv, v2T, (long long)(qbuf - v2T), uvec, cvec);
    // 5. energy[b] = q'_b @ h_b^T + c[t]  (f32, into dead hcat region)
    gemm256<0, 0, 3, 0><<<dim3(2, 2, 64), 512, 0, stream>>>(
        qbuf, h, energy, cvec, KR, KR, KR, 512, 512,
        512LL * KR, 512LL * KR, 512LL * 512, 0);
    // 6. softmax rows -> bf16 (into dead q' region)
    softmax_kernel<<<8192, 256, 0, stream>>>(energy, attn);
    // 7. out[b] = attn_b @ v2_b + (bv@W2 + b2)   f32 final output
    gemm256<0, 0, 1, 0><<<dim3(4, 2, 64), 512, 0, stream>>>(
        attn, v2T, out, b2p2, 512, 512, 512, 1024, 1024,
        512LL * 512, 1024LL * 512, 512LL * 1024, 0);
}

// Round 16
// 560.727 us; speedup vs baseline: 1.1198x; 1.0454x over previous
//
#include <hip/hip_runtime.h>
#include <hip/hip_bf16.h>
#include <cstdint>

typedef __hip_bfloat16 bf16;
typedef __attribute__((ext_vector_type(8))) short short8;
typedef __attribute__((ext_vector_type(4))) float f32x4;

// ---------------------------------------------------------------------------
// async global->LDS, 16B/lane (wave-uniform LDS base + lane*16 implicit)
// ---------------------------------------------------------------------------
__device__ __forceinline__ void gload16(const bf16* g, bf16* l) {
    __builtin_amdgcn_global_load_lds(
        (__attribute__((address_space(1))) void*)g,
        (__attribute__((address_space(3))) void*)l, 16, 0, 0);
}
#define VMC(n) asm volatile("s_waitcnt vmcnt(" #n ")" ::: "memory")
__device__ __forceinline__ void bar() {
    asm volatile("" ::: "memory");
    __builtin_amdgcn_s_barrier();
    asm volatile("" ::: "memory");
}

// ---------------------------------------------------------------------------
// stage one half-tile [128 rows x 64 cols bf16] into a linear LDS region.
// Source pre-swizzled: LDS(r, slot) = G(r, slot ^ (r&7)) [16B slots].
// ---------------------------------------------------------------------------
__device__ __forceinline__ void stage_half(const bf16* __restrict__ G, int ld,
                                           int row0, int k0, bf16* lregion,
                                           int w, int lrow, int lslot)
{
    const bf16* s0 = G + (long long)(row0 + w * 8 + lrow) * ld + (k0 + lslot * 8);
    gload16(s0, lregion + (w * 64) * 8);
    gload16(s0 + (long long)64 * ld, lregion + (512 + w * 64) * 8);
}

// round-7 lesson: each wave reads ONLY its own region (buf,op=A,half=wm); any
// fragment read of tile t requires BOTH A stages of t drained.
#define LOAD_AI(dst, i_, mh, P) do { \
    _Pragma("unroll") for (int ks_ = 0; ks_ < 2; ++ks_) \
      dst[i_][ks_] = *(const short8*)((P) + ((mh) * 64 + (i_) * 16 + l15) * 64 \
                                         + (((ks_ * 4 + lq) ^ l7) * 8)); } while (0)
#define LOAD_B(nh, dst) do { _Pragma("unroll") for (int j_ = 0; j_ < 2; ++j_) { \
    _Pragma("unroll") for (int ks_ = 0; ks_ < 2; ++ks_) \
      dst[j_][ks_] = *(const short8*)(pb + (bhr + (nh) * 32 + j_ * 16 + l15) * 64 \
                                         + (((ks_ * 4 + lq) ^ l7) * 8)); } } while (0)
#define DO_Q(mh, nh, AF, BF) do { \
    __builtin_amdgcn_s_setprio(1); \
    _Pragma("unroll") for (int i_ = 0; i_ < 4; ++i_) \
      _Pragma("unroll") for (int j_ = 0; j_ < 2; ++j_) \
        _Pragma("unroll") for (int ks_ = 0; ks_ < 2; ++ks_) \
          acc[mh][nh][i_][j_] = __builtin_amdgcn_mfma_f32_16x16x32_bf16( \
              AF[i_][ks_], BF[j_][ks_], acc[mh][nh][i_][j_], 0, 0, 0); \
    __builtin_amdgcn_s_setprio(0); \
} while (0)

// ---------------------------------------------------------------------------
// 256x256 8-phase bf16 GEMM core (r13 proven form), C = A*B^T (+bias)(+act).
// LDS 128 KiB: region(buf,op,half) = ldsb + ((buf*2+op)*2+half)*8192.
// BIASMODE: 0 none; 1 bias[gc]; 3 bias[bz*512+gc] (energy c[t] term).
// ROUTE: 0 single output; 2 dual (gc<1024 -> v2T direct; else q' ld 1088).
// ---------------------------------------------------------------------------
template<int OUT_BF16, int ACT, int BIASMODE, int ROUTE>
__device__ __forceinline__ void gemm_core(
    bf16* ldsb,
    const bf16* __restrict__ Abase, const bf16* __restrict__ Bbase,
    void* __restrict__ Cbase, const float* __restrict__ bias,
    int K, int lda, int ldb, int ldc, int nwrite,
    long long sA, long long sB, long long sC, long long segStride,
    int bx, int by, int bz)
{
    const int tid = threadIdx.x;
    const int wid = tid >> 6, lane = tid & 63;
    const int wm = wid >> 2, wn = wid & 3;          // 2 x 4 waves
    const int l15 = lane & 15, l7 = lane & 7, lq = lane >> 4;
    const int lrow = lane >> 3, lslot = l7 ^ lrow;  // staging per-lane geom
    const int bhr = (wn & 1) * 64;                  // B row base within half

    const bf16* A = Abase + (long long)bz * sA;
    const bf16* B = Bbase + (long long)bz * sB;
    const int brow = by * 256, bcol = bx * 256;

    f32x4 acc[2][2][4][2] = {};
    short8 aFe[4][2], aFo[4][2], bF0[2][2], bF1[2][2];

    const int nt = K >> 6;

    // ---- prologue: t0.B, t0.A -> buf0 ; t1.B -> buf1 ----
    stage_half(B, ldb, bcol,       0,  ldsb + 2 * 8192, wid, lrow, lslot);
    stage_half(B, ldb, bcol + 128, 0,  ldsb + 3 * 8192, wid, lrow, lslot);
    stage_half(A, lda, brow,       0,  ldsb,            wid, lrow, lslot);
    stage_half(A, lda, brow + 128, 0,  ldsb + 1 * 8192, wid, lrow, lslot);
    stage_half(B, ldb, bcol,       64, ldsb + 6 * 8192, wid, lrow, lslot);
    stage_half(B, ldb, bcol + 128, 64, ldsb + 7 * 8192, wid, lrow, lslot);
    VMC(4);   // drain B(0)+A(0); leaves B0(1),B1(1) = 4 (steady-state entry)
    bar();

    for (int t = 0; t < nt; ++t) {
        const int b = t & 1;
        const bf16* pa = ldsb + (b * 4 + wm) * 8192;
        const bf16* pb = ldsb + (b * 4 + 2 + (wn >> 1)) * 8192;
        bf16* oA = ldsb + ((b ^ 1) * 4) * 8192;   // next tile's A -> other buf
        bf16* cB = ldsb + (b * 4 + 2) * 8192;     // tile t+2's B -> current buf
        const int t1 = (t + 1 == nt) ? 0 : t + 1;
        const int t2 = (t + 2 >= nt) ? t + 2 - nt : t + 2;
        const int k1 = t1 << 6, k2 = t2 << 6;

        // ---- p1: read aFe + both B halves; stage A0(t+1); Q(0,0) ----
        LOAD_B(0, bF0);
        LOAD_AI(aFe, 0, 0, pa); LOAD_AI(aFe, 1, 0, pa);
        LOAD_AI(aFe, 2, 0, pa); LOAD_AI(aFe, 3, 0, pa);
        LOAD_B(1, bF1);
        stage_half(A, lda, brow, k1, oA, wid, lrow, lslot);
        bar();
        DO_Q(0, 0, aFe, bF0);
        bar();

        // ---- p2: read aFo[0,1]; stage A1(t+1); Q(0,1) ----
        LOAD_AI(aFo, 0, 1, pa); LOAD_AI(aFo, 1, 1, pa);
        stage_half(A, lda, brow + 128, k1, oA + 8192, wid, lrow, lslot);
        bar();
        DO_Q(0, 1, aFe, bF1);
        bar();

        // ---- p3: read aFo[2,3]; stage B0(t+2); Q(1,1) ----
        LOAD_AI(aFo, 2, 1, pa); LOAD_AI(aFo, 3, 1, pa);
        stage_half(B, ldb, bcol, k2, cB, wid, lrow, lslot);
        bar();
        DO_Q(1, 1, aFo, bF1);
        bar();

        // ---- p4: stage B1(t+2); Q(1,0); tile-boundary drain ----
        stage_half(B, ldb, bcol + 128, k2, cB + 8192, wid, lrow, lslot);
        bar();
        DO_Q(1, 0, aFo, bF0);
        VMC(4);   // drain B(t+1)+A(t+1); B(t+2) pair stays in flight
        bar();
    }
    VMC(0);   // drain wrapped stray stages

    // ---- epilogue: C/D layout col = lane&15, row = (lane>>4)*4 + rr ----
    const long long cofs0 = (long long)bz * sC;
    #pragma unroll
    for (int mh = 0; mh < 2; ++mh)
      #pragma unroll
      for (int nh = 0; nh < 2; ++nh)
        #pragma unroll
        for (int i = 0; i < 4; ++i)
          #pragma unroll
          for (int j = 0; j < 2; ++j) {
              const int gc = bcol + wn * 64 + nh * 32 + j * 16 + l15;
              const bool wr = gc < nwrite;
              const int row0 = brow + wm * 128 + mh * 64 + i * 16 + lq * 4;
              if (wr) {
                  float bvv = 0.0f;
                  if (BIASMODE == 1) bvv = bias[gc];
                  if (BIASMODE == 3) bvv = bias[(long long)bz * 512 + gc];
                  if (ROUTE == 2 && gc < 1024) {
                      // direct v2T write: v2T[(m>>9)*1024+gc][m&511]
                      const int b_ = row0 >> 9, s_ = row0 & 511;
                      bf16 t4[4];
                      #pragma unroll
                      for (int rr = 0; rr < 4; ++rr) {
                          float vv = acc[mh][nh][i][j][rr] + bvv;
                          t4[rr] = (bf16)vv;
                      }
                      *(ushort4*)&((bf16*)Cbase)[((long long)b_ * 1024 + gc) * 512 + s_]
                          = *(ushort4*)t4;
                  } else {
                      long long base; int lc, ld;
                      if (ROUTE == 2) { base = segStride; lc = gc - 1024; ld = 1088; }
                      else { base = cofs0; lc = gc; ld = ldc; }
                      #pragma unroll
                      for (int rr = 0; rr < 4; ++rr) {
                          float vv = acc[mh][nh][i][j][rr] + bvv;
                          if (ACT) vv = vv > 0.0f ? vv : 0.2f * vv;
                          const long long cidx = base + (long long)(row0 + rr) * ld + lc;
                          if (OUT_BF16) ((bf16*)Cbase)[cidx] = (bf16)vv;
                          else          ((float*)Cbase)[cidx] = vv;
                      }
                  }
              }
          }
}

// ---------------------------------------------------------------------------
// gemm256: thin wrapper with XCD-bijective swizzle (T1/m204)
// ---------------------------------------------------------------------------
template<int OUT_BF16, int ACT, int BIASMODE, int ROUTE>
__global__ __launch_bounds__(512, 2)
void gemm256(const bf16* __restrict__ Abase, const bf16* __restrict__ Bbase,
             void* __restrict__ Cbase, const float* __restrict__ bias,
             int K, int lda, int ldb, int ldc, int nwrite,
             long long sA, long long sB, long long sC, long long segStride)
{
    __shared__ bf16 lds[8][8192];
    const int gx = gridDim.x, gy = gridDim.y;
    const int nwg = gx * gy * gridDim.z;
    const int lin = blockIdx.x + gx * (blockIdx.y + gy * blockIdx.z);
    const int qch = nwg >> 3, rch = nwg & 7;
    const int xcd = lin & 7, pos = lin >> 3;
    const int nl = (xcd < rch ? xcd * (qch + 1)
                              : rch * (qch + 1) + (xcd - rch) * qch) + pos;
    const int bz = nl / (gx * gy);
    const int rem = nl - bz * (gx * gy);
    const int by = rem / gx;
    const int bx = rem - by * gx;
    gemm_core<OUT_BF16, ACT, BIASMODE, ROUTE>(
        &lds[0][0], Abase, Bbase, Cbase, bias, K, lda, ldb, ldc, nwrite,
        sA, sB, sC, segStride, bx, by, bz);
}

// ---------------------------------------------------------------------------
// mega0: heterogeneous dispatch overlapping the two weight GEMMs with
// concat + uvec + biasprep + bvw2.
// blocks [0,25): MT = Wk@Wq^T -> Bqv rows 1024.. ; [25,45): Wv2T -> Bqv 0..1023
// [45,8237): concat 4 rows/block; [8237,8373): uvec; [8373,8376): b1p;
// [8376,8392): bvw2.
// ---------------------------------------------------------------------------
__global__ __launch_bounds__(512, 2)
void mega0_kernel(const float* __restrict__ x, const float* __restrict__ emb,
                  const bf16* __restrict__ wkC, const bf16* __restrict__ wqC,
                  const bf16* __restrict__ w2T, const bf16* __restrict__ wvC,
                  bf16* __restrict__ Bqv, bf16* __restrict__ hcat,
                  const float* __restrict__ wk, const float* __restrict__ bq,
                  float* __restrict__ uvec,
                  const float* __restrict__ b1, float* __restrict__ b1p,
                  const float* __restrict__ bv, const float* __restrict__ w2,
                  const float* __restrict__ b2, float* __restrict__ b2p2)
{
    __shared__ bf16 lds[8][8192];
    const int lin = blockIdx.x;
    const int tid = threadIdx.x;
    if (lin < 25) {
        gemm_core<1, 0, 0, 0>(&lds[0][0], wkC, wqC, Bqv + 1024LL * 1088, nullptr,
                              1088, 1088, 1088, 1088, 1088, 0, 0, 0, 0,
                              lin % 5, lin / 5, 0);
    } else if (lin < 45) {
        const int l = lin - 25;
        gemm_core<1, 0, 0, 0>(&lds[0][0], w2T, wvC, Bqv, nullptr,
                              1088, 1088, 1088, 1088, 1088, 0, 0, 0, 0,
                              l % 5, l / 5, 0);
    } else if (lin < 8237) {
        // concat(x, emb) -> hcat [32768][1088]; 4 rows per block
        const int m = (lin - 45) * 4 + (tid >> 7);
        const int t = tid & 127;
        const int s = m & 511;
        const float* xr = x + (long long)m * 1024;
        bf16* orow = hcat + (long long)m * 1088;
        for (int g = t; g < 272; g += 128) {
            const int c = g * 4;
            float4 v;
            if (c < 1024)      v = *(const float4*)&xr[c];
            else if (c < 1056) v = *(const float4*)&emb[s * 32 + (c - 1024)];
            else               v = make_float4(0.f, 0.f, 0.f, 0.f);
            bf16 tt[4] = { (bf16)v.x, (bf16)v.y, (bf16)v.z, (bf16)v.w };
            *(ushort4*)&orow[c] = *(ushort4*)tt;
        }
    } else if (lin < 8373) {
        // uvec: u[e] = wk[e][:] . bq ; 8 e per block (8 waves)
        const int wid = tid >> 6, lane = tid & 63;
        const int e = (lin - 8237) * 8 + wid;
        if (e < 1088) {
            float s = 0.0f;
            if (e < 1056) {
                for (int d = lane; d < 1056; d += 64)
                    s += wk[(long long)e * 1056 + d] * bq[d];
            }
            #pragma unroll
            for (int sh = 32; sh > 0; sh >>= 1) s += __shfl_xor(s, sh);
            if (lane == 0) uvec[e] = s;
        }
    } else if (lin < 8376) {
        const int i = (lin - 8373) * 512 + tid;
        if (i < 1088) b1p[i] = (i < 1056) ? b1[i] : 0.0f;
    } else {
        // bvw2: b2p2[n] = b2[n] + bv . w2[:,n] ; 64 n per block, o split 8-way
        const int l = lin - 8376;
        const int nn = l * 64 + (tid & 63), oq = tid >> 6;
        float s = 0.0f;
        for (int o = oq; o < 1056; o += 8)
            s += bv[o] * w2[(long long)o * 1024 + nn];
        float* red = (float*)&lds[0][0];
        red[tid] = s;
        __syncthreads();
        if (tid < 64) {
            float t2 = b2[l * 64 + tid];
            #pragma unroll
            for (int q = 0; q < 8; ++q) t2 += red[q * 64 + tid];
            b2p2[l * 64 + tid] = t2;
        }
    }
}

// ---------------------------------------------------------------------------
// weight prep: z=0 w1->w1T[1280][1088] (transpose); z=1 wv->wvC pad-cast;
// z=2 w2->w2T[1024][1088] (transpose); z=3 wq->wqC pad-cast; z=4 wk->wkC.
// ---------------------------------------------------------------------------
__global__ void wprep_kernel(const float* __restrict__ w1, const float* __restrict__ wv,
                             const float* __restrict__ w2, const float* __restrict__ wq,
                             const float* __restrict__ wk,
                             bf16* __restrict__ w1T, bf16* __restrict__ wvC,
                             bf16* __restrict__ w2T, bf16* __restrict__ wqC,
                             bf16* __restrict__ wkC)
{
    const int z = blockIdx.z;
    const int tx = threadIdx.x, ty = threadIdx.y;
    if (z == 1 || z >= 3) {   // pad-cast, no transpose: dst [1280][1088]
        const float* src = (z == 1) ? wv : (z == 3) ? wq : wk;
        bf16* dst = (z == 1) ? wvC : (z == 3) ? wqC : wkC;
        const int r = blockIdx.y * 32 + ty, c = blockIdx.x * 32 + tx;
        if (r < 1280 && c < 1088) {
            float v = (r < 1056 && c < 1056) ? src[(long long)r * 1056 + c] : 0.0f;
            dst[(long long)r * 1088 + c] = (bf16)v;
        }
        return;
    }
    const float* src; bf16* dst; int NIN, NP, srcld;
    if (z == 0) { src = w1; dst = w1T; NIN = 1056; NP = 1280; srcld = 1056; }
    else        { src = w2; dst = w2T; NIN = 1024; NP = 1024; srcld = 1024; }
    const int KIN = 1056, KP = 1088;
    const int k0 = blockIdx.x * 32, n0 = blockIdx.y * 32;
    if (n0 >= NP) return;
    __shared__ float t[32][33];
    const int kk = k0 + ty, nn = n0 + tx;
    t[ty][tx] = (kk < KIN && nn < NIN) ? src[(long long)kk * srcld + nn] : 0.0f;
    __syncthreads();
    const int ko = k0 + tx, no = n0 + ty;
    if (no < NP && ko < KP)
        dst[(long long)no * KP + ko] = (bf16)t[tx][ty];
}

// ---------------------------------------------------------------------------
// c[m] = dot(h[m][0..1087], u); dynamic skip when u == 0 (bq == 0 case)
// ---------------------------------------------------------------------------
__global__ __launch_bounds__(256)
void cvec_kernel(const bf16* __restrict__ h, const float* __restrict__ u,
                 float* __restrict__ c)
{
    __shared__ float sred[256];
    __shared__ int nz;
    const int tid = threadIdx.x;
    float su = 0.0f;
    for (int i = tid; i < 1088; i += 256) su += fabsf(u[i]);
    sred[tid] = su;
    __syncthreads();
    if (tid < 128) sred[tid] += sred[tid + 128];
    __syncthreads();
    if (tid < 64) sred[tid] += sred[tid + 64];
    __syncthreads();
    if (tid == 0) {
        float t = 0.0f;
        for (int i = 0; i < 64; ++i) t += sred[i];
        nz = (t != 0.0f);
    }
    __syncthreads();
    const int wid = tid >> 6, lane = tid & 63;
    const long long row = (long long)blockIdx.x * 4 + wid;
    if (!nz) {
        if (lane == 0) c[row] = 0.0f;
        return;
    }
    const bf16* hr = h + row * 1088;
    float s = 0.0f;
    #pragma unroll
    for (int j = 0; j < 17; ++j)
        s += (float)hr[j * 64 + lane] * u[j * 64 + lane];
    #pragma unroll
    for (int sh = 32; sh > 0; sh >>= 1) s += __shfl_xor(s, sh);
    if (lane == 0) c[row] = s;
}

// ---------------------------------------------------------------------------
// row softmax: energy f32 [32768,512] -> attn bf16 [32768,512]; 1 wave/row
// ---------------------------------------------------------------------------
__global__ __launch_bounds__(256)
void softmax_kernel(const float* __restrict__ e, bf16* __restrict__ p)
{
    const int wid = threadIdx.x >> 6, lane = threadIdx.x & 63;
    const long long row = (long long)blockIdx.x * 4 + wid;
    const float* er = e + row * 512;
    float v[8];
    float mx = -3.0e38f;
    #pragma unroll
    for (int j = 0; j < 8; ++j) { v[j] = er[j * 64 + lane]; mx = fmaxf(mx, v[j]); }
    #pragma unroll
    for (int s = 32; s > 0; s >>= 1) mx = fmaxf(mx, __shfl_xor(mx, s));
    float sum = 0.0f;
    #pragma unroll
    for (int j = 0; j < 8; ++j) { v[j] = __expf(v[j] - mx); sum += v[j]; }
    #pragma unroll
    for (int s = 32; s > 0; s >>= 1) sum += __shfl_xor(sum, s);
    const float inv = 1.0f / sum;
    bf16* pr = p + row * 512;
    #pragma unroll
    for (int j = 0; j < 8; ++j) pr[j * 64 + lane] = (bf16)(v[j] * inv);
}

// ---------------------------------------------------------------------------
extern "C" void kernel_launch(void* const* d_in, const int* in_sizes, int n_in,
                              void* d_out, int out_size, void* d_ws, size_t ws_size,
                              hipStream_t stream)
{
    const float* x   = (const float*)d_in[0];
    const float* emb = (const float*)d_in[1];
    const float* w1  = (const float*)d_in[2];
    const float* b1  = (const float*)d_in[3];
    const float* wq  = (const float*)d_in[4];
    const float* bq  = (const float*)d_in[5];
    const float* wk  = (const float*)d_in[6];
    // const float* bk = (const float*)d_in[7];  // drops under softmax shift
    const float* wv  = (const float*)d_in[8];
    const float* bv  = (const float*)d_in[9];
    const float* w2  = (const float*)d_in[10];
    const float* b2  = (const float*)d_in[11];
    float* out = (float*)d_out;

    const long long Mrows = 32768;   // 64 * 512
    const int KR = 1088;             // compute K (17*64 >= 1056)

    char* ws = (char*)d_ws;
    size_t off = 0;
    auto alloc = [&](size_t bytes) -> char* {
        char* p = ws + off;
        off += (bytes + 255) & ~(size_t)255;
        return p;
    };
    char* R1   = alloc((size_t)Mrows * KR * 2);          // hcat -> energy
    char* Rh   = alloc((size_t)Mrows * KR * 2);          // h (lives to energy)
    char* Rq   = alloc((size_t)Mrows * KR * 2);          // q' -> attn
    bf16* v2T  = (bf16*)alloc((size_t)64 * 1024 * 512 * 2);
    bf16* w1T  = (bf16*)alloc((size_t)1280 * KR * 2);
    bf16* Bqv  = (bf16*)alloc((size_t)2304 * KR * 2);    // [0..1023]=Wv2T, [1024..]=M^T
    bf16* w2T  = (bf16*)alloc((size_t)1024 * KR * 2);
    bf16* wqC  = (bf16*)alloc((size_t)1280 * KR * 2);
    bf16* wkC  = (bf16*)alloc((size_t)1280 * KR * 2);
    bf16* wvC  = (bf16*)alloc((size_t)1280 * KR * 2);
    float* b1p  = (float*)alloc((size_t)1088 * 4);
    float* b2p2 = (float*)alloc((size_t)1024 * 4);
    float* uvec = (float*)alloc((size_t)1088 * 4);
    float* cvec = (float*)alloc((size_t)Mrows * 4);

    bf16*  hcat   = (bf16*)R1;
    float* energy = (float*)R1;       // after l1 consumed hcat (67<=71MB)
    bf16*  h      = (bf16*)Rh;        // [32768][1088], alive until energy
    bf16*  qbuf   = (bf16*)Rq;        // q' [32768][1088]
    bf16*  attn   = (bf16*)Rq;        // after energy consumed q'

    // 1. weight transpose/cast prep
    wprep_kernel<<<dim3(34, 40, 5), dim3(32, 32), 0, stream>>>(
        w1, wv, w2, wq, wk, w1T, wvC, w2T, wqC, wkC);
    // 2. mega0: {MT, Wv2T} GEMMs || concat || uvec || b1p || bvw2
    mega0_kernel<<<8392, 512, 0, stream>>>(
        x, emb, wkC, wqC, w2T, wvC, Bqv, hcat,
        wk, bq, uvec, b1, b1p, bv, w2, b2, b2p2);
    // 3. h = leaky_relu(hcat @ w1^T + b1)   M=32768 Ngrid=1280 K=1088
    gemm256<1, 1, 1, 0><<<dim3(5, 128, 1), 512, 0, stream>>>(
        hcat, w1T, h, b1p, KR, KR, KR, KR, KR, 0, 0, 0, 0);
    // 4. c[m] = h[m] . u  (skips h read when u == 0)
    cvec_kernel<<<8192, 256, 0, stream>>>(h, uvec, cvec);
    // 5. v2(->v2T direct) | q' = h @ Bqv^T   M=32768 Ngrid=2304 K=1088
    gemm256<1, 0, 0, 2><<<dim3(9, 128, 1), 512, 0, stream>>>(
        h, Bqv, v2T, nullptr, KR, KR, KR, 0, 2112, 0, 0, 0,
        (long long)(qbuf - v2T));
    // 6. energy[b] = q'_b @ h_b^T + c[t]  (f32, into dead hcat region)
    gemm256<0, 0, 3, 0><<<dim3(2, 2, 64), 512, 0, stream>>>(
        qbuf, h, energy, cvec, KR, KR, KR, 512, 512,
        512LL * KR, 512LL * KR, 512LL * 512, 0);
    // 7. softmax rows -> bf16 (into dead q' region)
    softmax_kernel<<<8192, 256, 0, stream>>>(energy, attn);
    // 8. out[b] = attn_b @ v2_b + (bv@W2 + b2)   f32 final output
    gemm256<0, 0, 1, 0><<<dim3(4, 2, 64), 512, 0, stream>>>(
        attn, v2T, out, b2p2, 512, 512, 512, 1024, 1024,
        512LL * 512, 1024LL * 512, 512LL * 1024, 0);
}

// Round 17
// 539.727 us; speedup vs baseline: 1.1634x; 1.0389x over previous
//
#include <hip/hip_runtime.h>
#include <hip/hip_bf16.h>
#include <cstdint>

typedef __hip_bfloat16 bf16;
typedef __attribute__((ext_vector_type(8))) short short8;
typedef __attribute__((ext_vector_type(4))) float f32x4;

// ---------------------------------------------------------------------------
// async global->LDS, 16B/lane (wave-uniform LDS base + lane*16 implicit)
// ---------------------------------------------------------------------------
__device__ __forceinline__ void gload16(const bf16* g, bf16* l) {
    __builtin_amdgcn_global_load_lds(
        (__attribute__((address_space(1))) void*)g,
        (__attribute__((address_space(3))) void*)l, 16, 0, 0);
}
#define VMC(n) asm volatile("s_waitcnt vmcnt(" #n ")" ::: "memory")
__device__ __forceinline__ void bar() {
    asm volatile("" ::: "memory");
    __builtin_amdgcn_s_barrier();
    asm volatile("" ::: "memory");
}

// ---------------------------------------------------------------------------
// stage one half-tile [128 rows x 64 cols bf16] into a linear LDS region.
// Source pre-swizzled: LDS(r, slot) = G(r, slot ^ (r&7)) [16B slots].
// ---------------------------------------------------------------------------
__device__ __forceinline__ void stage_half(const bf16* __restrict__ G, int ld,
                                           int row0, int k0, bf16* lregion,
                                           int w, int lrow, int lslot)
{
    const bf16* s0 = G + (long long)(row0 + w * 8 + lrow) * ld + (k0 + lslot * 8);
    gload16(s0, lregion + (w * 64) * 8);
    gload16(s0 + (long long)64 * ld, lregion + (512 + w * 64) * 8);
}

// round-7 lesson: each wave reads ONLY its own region (buf,op=A,half=wm); any
// fragment read of tile t requires BOTH A stages of t drained.
#define LOAD_AI(dst, i_, mh, P) do { \
    _Pragma("unroll") for (int ks_ = 0; ks_ < 2; ++ks_) \
      dst[i_][ks_] = *(const short8*)((P) + ((mh) * 64 + (i_) * 16 + l15) * 64 \
                                         + (((ks_ * 4 + lq) ^ l7) * 8)); } while (0)
#define LOAD_B(nh, dst) do { _Pragma("unroll") for (int j_ = 0; j_ < 2; ++j_) { \
    _Pragma("unroll") for (int ks_ = 0; ks_ < 2; ++ks_) \
      dst[j_][ks_] = *(const short8*)(pb + (bhr + (nh) * 32 + j_ * 16 + l15) * 64 \
                                         + (((ks_ * 4 + lq) ^ l7) * 8)); } } while (0)
#define DO_Q(mh, nh, AF, BF) do { \
    __builtin_amdgcn_s_setprio(1); \
    _Pragma("unroll") for (int i_ = 0; i_ < 4; ++i_) \
      _Pragma("unroll") for (int j_ = 0; j_ < 2; ++j_) \
        _Pragma("unroll") for (int ks_ = 0; ks_ < 2; ++ks_) \
          acc[mh][nh][i_][j_] = __builtin_amdgcn_mfma_f32_16x16x32_bf16( \
              AF[i_][ks_], BF[j_][ks_], acc[mh][nh][i_][j_], 0, 0, 0); \
    __builtin_amdgcn_s_setprio(0); \
} while (0)

// ---------------------------------------------------------------------------
// 256x256 8-phase bf16 GEMM core (r13 proven form), C = A*B^T (+bias)(+act).
// LDS 128 KiB: region(buf,op,half) = ldsb + ((buf*2+op)*2+half)*8192.
// BIASMODE: 0 none; 1 bias[gc]; 3 bias[bz*512+gc] (energy c[t] term).
// ROUTE: 0 single output; 2 dual (gc<1024 -> v2T direct; else q' ld 1088).
// ---------------------------------------------------------------------------
template<int OUT_BF16, int ACT, int BIASMODE, int ROUTE>
__device__ __forceinline__ void gemm_core(
    bf16* ldsb,
    const bf16* __restrict__ Abase, const bf16* __restrict__ Bbase,
    void* __restrict__ Cbase, const float* __restrict__ bias,
    int K, int lda, int ldb, int ldc, int nwrite,
    long long sA, long long sB, long long sC, long long segStride,
    int bx, int by, int bz)
{
    const int tid = threadIdx.x;
    const int wid = tid >> 6, lane = tid & 63;
    const int wm = wid >> 2, wn = wid & 3;          // 2 x 4 waves
    const int l15 = lane & 15, l7 = lane & 7, lq = lane >> 4;
    const int lrow = lane >> 3, lslot = l7 ^ lrow;  // staging per-lane geom
    const int bhr = (wn & 1) * 64;                  // B row base within half

    const bf16* A = Abase + (long long)bz * sA;
    const bf16* B = Bbase + (long long)bz * sB;
    const int brow = by * 256, bcol = bx * 256;

    f32x4 acc[2][2][4][2] = {};
    short8 aFe[4][2], aFo[4][2], bF0[2][2], bF1[2][2];

    const int nt = K >> 6;

    // ---- prologue: t0.B, t0.A -> buf0 ; t1.B -> buf1 ----
    stage_half(B, ldb, bcol,       0,  ldsb + 2 * 8192, wid, lrow, lslot);
    stage_half(B, ldb, bcol + 128, 0,  ldsb + 3 * 8192, wid, lrow, lslot);
    stage_half(A, lda, brow,       0,  ldsb,            wid, lrow, lslot);
    stage_half(A, lda, brow + 128, 0,  ldsb + 1 * 8192, wid, lrow, lslot);
    stage_half(B, ldb, bcol,       64, ldsb + 6 * 8192, wid, lrow, lslot);
    stage_half(B, ldb, bcol + 128, 64, ldsb + 7 * 8192, wid, lrow, lslot);
    VMC(4);   // drain B(0)+A(0); leaves B0(1),B1(1) = 4 (steady-state entry)
    bar();

    for (int t = 0; t < nt; ++t) {
        const int b = t & 1;
        const bf16* pa = ldsb + (b * 4 + wm) * 8192;
        const bf16* pb = ldsb + (b * 4 + 2 + (wn >> 1)) * 8192;
        bf16* oA = ldsb + ((b ^ 1) * 4) * 8192;   // next tile's A -> other buf
        bf16* cB = ldsb + (b * 4 + 2) * 8192;     // tile t+2's B -> current buf
        const int t1 = (t + 1 == nt) ? 0 : t + 1;
        const int t2 = (t + 2 >= nt) ? t + 2 - nt : t + 2;
        const int k1 = t1 << 6, k2 = t2 << 6;

        // ---- p1: read aFe + both B halves; stage A0(t+1); Q(0,0) ----
        LOAD_B(0, bF0);
        LOAD_AI(aFe, 0, 0, pa); LOAD_AI(aFe, 1, 0, pa);
        LOAD_AI(aFe, 2, 0, pa); LOAD_AI(aFe, 3, 0, pa);
        LOAD_B(1, bF1);
        stage_half(A, lda, brow, k1, oA, wid, lrow, lslot);
        bar();
        DO_Q(0, 0, aFe, bF0);
        bar();

        // ---- p2: read aFo[0,1]; stage A1(t+1); Q(0,1) ----
        LOAD_AI(aFo, 0, 1, pa); LOAD_AI(aFo, 1, 1, pa);
        stage_half(A, lda, brow + 128, k1, oA + 8192, wid, lrow, lslot);
        bar();
        DO_Q(0, 1, aFe, bF1);
        bar();

        // ---- p3: read aFo[2,3]; stage B0(t+2); Q(1,1) ----
        LOAD_AI(aFo, 2, 1, pa); LOAD_AI(aFo, 3, 1, pa);
        stage_half(B, ldb, bcol, k2, cB, wid, lrow, lslot);
        bar();
        DO_Q(1, 1, aFo, bF1);
        bar();

        // ---- p4: stage B1(t+2); Q(1,0); tile-boundary drain ----
        stage_half(B, ldb, bcol + 128, k2, cB + 8192, wid, lrow, lslot);
        bar();
        DO_Q(1, 0, aFo, bF0);
        VMC(4);   // drain B(t+1)+A(t+1); B(t+2) pair stays in flight
        bar();
    }
    VMC(0);   // drain wrapped stray stages

    // ---- epilogue: C/D layout col = lane&15, row = (lane>>4)*4 + rr ----
    const long long cofs0 = (long long)bz * sC;
    #pragma unroll
    for (int mh = 0; mh < 2; ++mh)
      #pragma unroll
      for (int nh = 0; nh < 2; ++nh)
        #pragma unroll
        for (int i = 0; i < 4; ++i)
          #pragma unroll
          for (int j = 0; j < 2; ++j) {
              const int gc = bcol + wn * 64 + nh * 32 + j * 16 + l15;
              const bool wr = gc < nwrite;
              const int row0 = brow + wm * 128 + mh * 64 + i * 16 + lq * 4;
              if (wr) {
                  float bvv = 0.0f;
                  if (BIASMODE == 1) bvv = bias[gc];
                  if (BIASMODE == 3) bvv = bias[(long long)bz * 512 + gc];
                  if (ROUTE == 2 && gc < 1024) {
                      // direct v2T write: v2T[(m>>9)*1024+gc][m&511]
                      const int b_ = row0 >> 9, s_ = row0 & 511;
                      bf16 t4[4];
                      #pragma unroll
                      for (int rr = 0; rr < 4; ++rr) {
                          float vv = acc[mh][nh][i][j][rr] + bvv;
                          t4[rr] = (bf16)vv;
                      }
                      *(ushort4*)&((bf16*)Cbase)[((long long)b_ * 1024 + gc) * 512 + s_]
                          = *(ushort4*)t4;
                  } else {
                      long long base; int lc, ld;
                      if (ROUTE == 2) { base = segStride; lc = gc - 1024; ld = 1088; }
                      else { base = cofs0; lc = gc; ld = ldc; }
                      #pragma unroll
                      for (int rr = 0; rr < 4; ++rr) {
                          float vv = acc[mh][nh][i][j][rr] + bvv;
                          if (ACT) vv = vv > 0.0f ? vv : 0.2f * vv;
                          const long long cidx = base + (long long)(row0 + rr) * ld + lc;
                          if (OUT_BF16) ((bf16*)Cbase)[cidx] = (bf16)vv;
                          else          ((float*)Cbase)[cidx] = vv;
                      }
                  }
              }
          }
}

// ---------------------------------------------------------------------------
// gemm256: thin wrapper with XCD-bijective swizzle (T1/m204)
// ---------------------------------------------------------------------------
template<int OUT_BF16, int ACT, int BIASMODE, int ROUTE>
__global__ __launch_bounds__(512, 2)
void gemm256(const bf16* __restrict__ Abase, const bf16* __restrict__ Bbase,
             void* __restrict__ Cbase, const float* __restrict__ bias,
             int K, int lda, int ldb, int ldc, int nwrite,
             long long sA, long long sB, long long sC, long long segStride)
{
    __shared__ bf16 lds[8][8192];
    const int gx = gridDim.x, gy = gridDim.y;
    const int nwg = gx * gy * gridDim.z;
    const int lin = blockIdx.x + gx * (blockIdx.y + gy * blockIdx.z);
    const int qch = nwg >> 3, rch = nwg & 7;
    const int xcd = lin & 7, pos = lin >> 3;
    const int nl = (xcd < rch ? xcd * (qch + 1)
                              : rch * (qch + 1) + (xcd - rch) * qch) + pos;
    const int bz = nl / (gx * gy);
    const int rem = nl - bz * (gx * gy);
    const int by = rem / gx;
    const int bx = rem - by * gx;
    gemm_core<OUT_BF16, ACT, BIASMODE, ROUTE>(
        &lds[0][0], Abase, Bbase, Cbase, bias, K, lda, ldb, ldc, nwrite,
        sA, sB, sC, segStride, bx, by, bz);
}

// ---------------------------------------------------------------------------
// mega0: heterogeneous dispatch overlapping the two weight GEMMs with
// concat + uvec + biasprep + bvw2.
// blocks [0,25): MT = Wk@Wq^T -> Bqv rows 1024.. ; [25,45): Wv2T -> Bqv 0..1023
// [45,8237): concat 4 rows/block; [8237,8373): uvec; [8373,8376): b1p;
// [8376,8392): bvw2.
// ---------------------------------------------------------------------------
__global__ __launch_bounds__(512, 2)
void mega0_kernel(const float* __restrict__ x, const float* __restrict__ emb,
                  const bf16* __restrict__ wkC, const bf16* __restrict__ wqC,
                  const bf16* __restrict__ w2T, const bf16* __restrict__ wvC,
                  bf16* __restrict__ Bqv, bf16* __restrict__ hcat,
                  const float* __restrict__ wk, const float* __restrict__ bq,
                  float* __restrict__ uvec,
                  const float* __restrict__ b1, float* __restrict__ b1p,
                  const float* __restrict__ bv, const float* __restrict__ w2,
                  const float* __restrict__ b2, float* __restrict__ b2p2)
{
    __shared__ bf16 lds[8][8192];
    const int lin = blockIdx.x;
    const int tid = threadIdx.x;
    if (lin < 25) {
        gemm_core<1, 0, 0, 0>(&lds[0][0], wkC, wqC, Bqv + 1024LL * 1088, nullptr,
                              1088, 1088, 1088, 1088, 1088, 0, 0, 0, 0,
                              lin % 5, lin / 5, 0);
    } else if (lin < 45) {
        const int l = lin - 25;
        gemm_core<1, 0, 0, 0>(&lds[0][0], w2T, wvC, Bqv, nullptr,
                              1088, 1088, 1088, 1088, 1088, 0, 0, 0, 0,
                              l % 5, l / 5, 0);
    } else if (lin < 8237) {
        // concat(x, emb) -> hcat [32768][1088]; 4 rows per block
        const int m = (lin - 45) * 4 + (tid >> 7);
        const int t = tid & 127;
        const int s = m & 511;
        const float* xr = x + (long long)m * 1024;
        bf16* orow = hcat + (long long)m * 1088;
        for (int g = t; g < 272; g += 128) {
            const int c = g * 4;
            float4 v;
            if (c < 1024)      v = *(const float4*)&xr[c];
            else if (c < 1056) v = *(const float4*)&emb[s * 32 + (c - 1024)];
            else               v = make_float4(0.f, 0.f, 0.f, 0.f);
            bf16 tt[4] = { (bf16)v.x, (bf16)v.y, (bf16)v.z, (bf16)v.w };
            *(ushort4*)&orow[c] = *(ushort4*)tt;
        }
    } else if (lin < 8373) {
        // uvec: u[e] = wk[e][:] . bq ; 8 e per block (8 waves)
        const int wid = tid >> 6, lane = tid & 63;
        const int e = (lin - 8237) * 8 + wid;
        if (e < 1088) {
            float s = 0.0f;
            if (e < 1056) {
                for (int d = lane; d < 1056; d += 64)
                    s += wk[(long long)e * 1056 + d] * bq[d];
            }
            #pragma unroll
            for (int sh = 32; sh > 0; sh >>= 1) s += __shfl_xor(s, sh);
            if (lane == 0) uvec[e] = s;
        }
    } else if (lin < 8376) {
        const int i = (lin - 8373) * 512 + tid;
        if (i < 1088) b1p[i] = (i < 1056) ? b1[i] : 0.0f;
    } else {
        // bvw2: b2p2[n] = b2[n] + bv . w2[:,n] ; 64 n per block, o split 8-way
        const int l = lin - 8376;
        const int nn = l * 64 + (tid & 63), oq = tid >> 6;
        float s = 0.0f;
        for (int o = oq; o < 1056; o += 8)
            s += bv[o] * w2[(long long)o * 1024 + nn];
        float* red = (float*)&lds[0][0];
        red[tid] = s;
        __syncthreads();
        if (tid < 64) {
            float t2 = b2[l * 64 + tid];
            #pragma unroll
            for (int q = 0; q < 8; ++q) t2 += red[q * 64 + tid];
            b2p2[l * 64 + tid] = t2;
        }
    }
}

// ---------------------------------------------------------------------------
// weight prep: z=0 w1->w1T[1280][1088] (transpose); z=1 wv->wvC pad-cast;
// z=2 w2->w2T[1024][1088] (transpose); z=3 wq->wqC pad-cast; z=4 wk->wkC.
// ---------------------------------------------------------------------------
__global__ void wprep_kernel(const float* __restrict__ w1, const float* __restrict__ wv,
                             const float* __restrict__ w2, const float* __restrict__ wq,
                             const float* __restrict__ wk,
                             bf16* __restrict__ w1T, bf16* __restrict__ wvC,
                             bf16* __restrict__ w2T, bf16* __restrict__ wqC,
                             bf16* __restrict__ wkC)
{
    const int z = blockIdx.z;
    const int tx = threadIdx.x, ty = threadIdx.y;
    if (z == 1 || z >= 3) {   // pad-cast, no transpose: dst [1280][1088]
        const float* src = (z == 1) ? wv : (z == 3) ? wq : wk;
        bf16* dst = (z == 1) ? wvC : (z == 3) ? wqC : wkC;
        const int r = blockIdx.y * 32 + ty, c = blockIdx.x * 32 + tx;
        if (r < 1280 && c < 1088) {
            float v = (r < 1056 && c < 1056) ? src[(long long)r * 1056 + c] : 0.0f;
            dst[(long long)r * 1088 + c] = (bf16)v;
        }
        return;
    }
    const float* src; bf16* dst; int NIN, NP, srcld;
    if (z == 0) { src = w1; dst = w1T; NIN = 1056; NP = 1280; srcld = 1056; }
    else        { src = w2; dst = w2T; NIN = 1024; NP = 1024; srcld = 1024; }
    const int KIN = 1056, KP = 1088;
    const int k0 = blockIdx.x * 32, n0 = blockIdx.y * 32;
    if (n0 >= NP) return;
    __shared__ float t[32][33];
    const int kk = k0 + ty, nn = n0 + tx;
    t[ty][tx] = (kk < KIN && nn < NIN) ? src[(long long)kk * srcld + nn] : 0.0f;
    __syncthreads();
    const int ko = k0 + tx, no = n0 + ty;
    if (no < NP && ko < KP)
        dst[(long long)no * KP + ko] = (bf16)t[tx][ty];
}

// ---------------------------------------------------------------------------
// c[m] = dot(h[m][0..1087], u); dynamic skip when u == 0 (bq == 0 case)
// ---------------------------------------------------------------------------
__global__ __launch_bounds__(256)
void cvec_kernel(const bf16* __restrict__ h, const float* __restrict__ u,
                 float* __restrict__ c)
{
    __shared__ float sred[256];
    __shared__ int nz;
    const int tid = threadIdx.x;
    float su = 0.0f;
    for (int i = tid; i < 1088; i += 256) su += fabsf(u[i]);
    sred[tid] = su;
    __syncthreads();
    if (tid < 128) sred[tid] += sred[tid + 128];
    __syncthreads();
    if (tid < 64) sred[tid] += sred[tid + 64];
    __syncthreads();
    if (tid == 0) {
        float t = 0.0f;
        for (int i = 0; i < 64; ++i) t += sred[i];
        nz = (t != 0.0f);
    }
    __syncthreads();
    const int wid = tid >> 6, lane = tid & 63;
    const long long row = (long long)blockIdx.x * 4 + wid;
    if (!nz) {
        if (lane == 0) c[row] = 0.0f;
        return;
    }
    const bf16* hr = h + row * 1088;
    float s = 0.0f;
    #pragma unroll
    for (int j = 0; j < 17; ++j)
        s += (float)hr[j * 64 + lane] * u[j * 64 + lane];
    #pragma unroll
    for (int sh = 32; sh > 0; sh >>= 1) s += __shfl_xor(s, sh);
    if (lane == 0) c[row] = s;
}

// ---------------------------------------------------------------------------
// row softmax: energy bf16 [32768,512] -> attn bf16 [32768,512]; 1 wave/row,
// lane-contiguous short8 loads/stores (G13).
// ---------------------------------------------------------------------------
__global__ __launch_bounds__(256)
void softmax_kernel(const bf16* __restrict__ e, bf16* __restrict__ p)
{
    const int wid = threadIdx.x >> 6, lane = threadIdx.x & 63;
    const long long row = (long long)blockIdx.x * 4 + wid;
    const bf16* er = e + row * 512;
    const short8 raw = *(const short8*)&er[lane * 8];
    float v[8];
    float mx = -3.0e38f;
    #pragma unroll
    for (int j = 0; j < 8; ++j) {
        unsigned short u = (unsigned short)raw[j];
        union { unsigned int i; float f; } cv;
        cv.i = ((unsigned int)u) << 16;
        v[j] = cv.f;
        mx = fmaxf(mx, v[j]);
    }
    #pragma unroll
    for (int s = 32; s > 0; s >>= 1) mx = fmaxf(mx, __shfl_xor(mx, s));
    float sum = 0.0f;
    #pragma unroll
    for (int j = 0; j < 8; ++j) { v[j] = __expf(v[j] - mx); sum += v[j]; }
    #pragma unroll
    for (int s = 32; s > 0; s >>= 1) sum += __shfl_xor(sum, s);
    const float inv = 1.0f / sum;
    bf16 t[8];
    #pragma unroll
    for (int j = 0; j < 8; ++j) t[j] = (bf16)(v[j] * inv);
    *(short8*)&p[row * 512 + lane * 8] = *(short8*)t;
}

// ---------------------------------------------------------------------------
extern "C" void kernel_launch(void* const* d_in, const int* in_sizes, int n_in,
                              void* d_out, int out_size, void* d_ws, size_t ws_size,
                              hipStream_t stream)
{
    const float* x   = (const float*)d_in[0];
    const float* emb = (const float*)d_in[1];
    const float* w1  = (const float*)d_in[2];
    const float* b1  = (const float*)d_in[3];
    const float* wq  = (const float*)d_in[4];
    const float* bq  = (const float*)d_in[5];
    const float* wk  = (const float*)d_in[6];
    // const float* bk = (const float*)d_in[7];  // drops under softmax shift
    const float* wv  = (const float*)d_in[8];
    const float* bv  = (const float*)d_in[9];
    const float* w2  = (const float*)d_in[10];
    const float* b2  = (const float*)d_in[11];
    float* out = (float*)d_out;

    const long long Mrows = 32768;   // 64 * 512
    const int KR = 1088;             // compute K (17*64 >= 1056)

    char* ws = (char*)d_ws;
    size_t off = 0;
    auto alloc = [&](size_t bytes) -> char* {
        char* p = ws + off;
        off += (bytes + 255) & ~(size_t)255;
        return p;
    };
    char* R1   = alloc((size_t)Mrows * KR * 2);          // hcat -> energy(bf16)
    char* Rh   = alloc((size_t)Mrows * KR * 2);          // h (lives to energy)
    char* Rq   = alloc((size_t)Mrows * KR * 2);          // q' -> attn
    bf16* v2T  = (bf16*)alloc((size_t)64 * 1024 * 512 * 2);
    bf16* w1T  = (bf16*)alloc((size_t)1280 * KR * 2);
    bf16* Bqv  = (bf16*)alloc((size_t)2304 * KR * 2);    // [0..1023]=Wv2T, [1024..]=M^T
    bf16* w2T  = (bf16*)alloc((size_t)1024 * KR * 2);
    bf16* wqC  = (bf16*)alloc((size_t)1280 * KR * 2);
    bf16* wkC  = (bf16*)alloc((size_t)1280 * KR * 2);
    bf16* wvC  = (bf16*)alloc((size_t)1280 * KR * 2);
    float* b1p  = (float*)alloc((size_t)1088 * 4);
    float* b2p2 = (float*)alloc((size_t)1024 * 4);
    float* uvec = (float*)alloc((size_t)1088 * 4);
    float* cvec = (float*)alloc((size_t)Mrows * 4);

    bf16*  hcat   = (bf16*)R1;
    bf16*  energy = (bf16*)R1;        // bf16 energy after l1 consumed hcat
    bf16*  h      = (bf16*)Rh;        // [32768][1088], alive until energy
    bf16*  qbuf   = (bf16*)Rq;        // q' [32768][1088]
    bf16*  attn   = (bf16*)Rq;        // after energy consumed q'

    // 1. weight transpose/cast prep
    wprep_kernel<<<dim3(34, 40, 5), dim3(32, 32), 0, stream>>>(
        w1, wv, w2, wq, wk, w1T, wvC, w2T, wqC, wkC);
    // 2. mega0: {MT, Wv2T} GEMMs || concat || uvec || b1p || bvw2
    mega0_kernel<<<8392, 512, 0, stream>>>(
        x, emb, wkC, wqC, w2T, wvC, Bqv, hcat,
        wk, bq, uvec, b1, b1p, bv, w2, b2, b2p2);
    // 3. h = leaky_relu(hcat @ w1^T + b1)   M=32768 Ngrid=1280 K=1088
    gemm256<1, 1, 1, 0><<<dim3(5, 128, 1), 512, 0, stream>>>(
        hcat, w1T, h, b1p, KR, KR, KR, KR, KR, 0, 0, 0, 0);
    // 4. c[m] = h[m] . u  (skips h read when u == 0)
    cvec_kernel<<<8192, 256, 0, stream>>>(h, uvec, cvec);
    // 5. v2(->v2T direct) | q' = h @ Bqv^T   M=32768 Ngrid=2304 K=1088
    gemm256<1, 0, 0, 2><<<dim3(9, 128, 1), 512, 0, stream>>>(
        h, Bqv, v2T, nullptr, KR, KR, KR, 0, 2112, 0, 0, 0,
        (long long)(qbuf - v2T));
    // 6. energy[b] = q'_b @ h_b^T + c[t]  (bf16 out, into dead hcat region)
    gemm256<1, 0, 3, 0><<<dim3(2, 2, 64), 512, 0, stream>>>(
        qbuf, h, energy, cvec, KR, KR, KR, 512, 512,
        512LL * KR, 512LL * KR, 512LL * 512, 0);
    // 7. softmax rows (bf16 in) -> attn bf16 (into dead q' region)
    softmax_kernel<<<8192, 256, 0, stream>>>(energy, attn);
    // 8. out[b] = attn_b @ v2_b + (bv@W2 + b2)   f32 final output
    gemm256<0, 0, 1, 0><<<dim3(4, 2, 64), 512, 0, stream>>>(
        attn, v2T, out, b2p2, 512, 512, 512, 1024, 1024,
        512LL * 512, 1024LL * 512, 512LL * 1024, 0);
}